// Round 1
// baseline (759.932 us; speedup 1.0000x reference)
//
#include <hip/hip_runtime.h>
#include <hip/hip_bf16.h>
#include <cstdint>

// Problem constants (fixed by the reference)
#define NN 10000      // nodes
#define NE 320000     // edges
#define NC 256        // node channels
#define OC 512        // out channels
#define KT 768        // 2*NC + 256 (edge attr)

typedef __bf16 bf16_t;
typedef bf16_t bf16x8 __attribute__((ext_vector_type(8)));
typedef float  f32x4  __attribute__((ext_vector_type(4)));

// ---------------------------------------------------------------------------
// Prep: zero agg/deg/sums, convert x -> bf16, build W1' and W2 transposed
// [n][k] bf16.  W1' folds the (x_j - x_i) term:  W1'a = W1a - W1b.
// ---------------------------------------------------------------------------
__global__ void k_prep(const float* __restrict__ x,
                       const float* __restrict__ W1,
                       const float* __restrict__ W2,
                       bf16_t* __restrict__ xb,
                       bf16_t* __restrict__ w1t,
                       bf16_t* __restrict__ w2t,
                       float* __restrict__ agg,
                       int* __restrict__ deg,
                       float* __restrict__ sums) {
  const int stride = gridDim.x * blockDim.x;
  for (int i = blockIdx.x * blockDim.x + threadIdx.x; i < NN * OC; i += stride) {
    agg[i] = 0.0f;
    if (i < NN * NC) xb[i] = (bf16_t)x[i];
    if (i < OC * KT) {
      const int n = i / KT, k = i - n * KT;
      float w = W1[(size_t)k * OC + n];
      if (k < NC) w = w - W1[(size_t)(k + NC) * OC + n];  // W1a - W1b
      w1t[i] = (bf16_t)w;
    }
    if (i < OC * OC) {
      const int n = i >> 9, k = i & 511;
      w2t[i] = (bf16_t)W2[(size_t)k * OC + n];
    }
    if (i < NN) deg[i] = 0;
    if (i < 2048) sums[i] = 0.0f;
  }
}

__global__ void k_deg(const int* __restrict__ dstIdx, int* __restrict__ deg) {
  const int i = blockIdx.x * blockDim.x + threadIdx.x;
  if (i < NE) atomicAdd(&deg[dstIdx[i]], 1);
}

// ---------------------------------------------------------------------------
// Edge GEMM: per 128-edge x 128-col tile, K=768 in steps of 64.
// m' = [x_i | x_j | ea] (pure gathers thanks to W1' folding).
// Epilogue: relu(acc + b1) atomically accumulated into agg[dst].
// ---------------------------------------------------------------------------
__global__ __launch_bounds__(256) void k_edge_gemm(
    const bf16_t* __restrict__ xb,     // [NN][NC] bf16
    const float*  __restrict__ ea,     // [NE][NC] f32
    const bf16_t* __restrict__ w1t,    // [OC][KT] bf16 (transposed W1')
    const float*  __restrict__ b1,
    const int*    __restrict__ srcIdx,
    const int*    __restrict__ dstIdx,
    float*        __restrict__ agg) {  // [NN][OC] f32
  __shared__ bf16_t sM[128 * 72];      // [edge][k] pad 72 (2-way free)
  __shared__ bf16_t sW[128 * 72];      // [col][k]  pad 72
  __shared__ int sDst[128];
  __shared__ int sSrc[128];

  const int tid  = threadIdx.x;
  const int bid  = blockIdx.x;
  const int cb   = bid & 3;        // col-block fastest: edge tile reused via L2/L3
  const int eblk = bid >> 2;
  const int e0   = eblk * 128;
  const int n0   = cb * 128;

  if (tid < 128) { sDst[tid] = dstIdx[e0 + tid]; sSrc[tid] = srcIdx[e0 + tid]; }
  __syncthreads();

  const int lane  = tid & 63, wid = tid >> 6;
  const int mbase = (wid >> 1) * 64, nbase = (wid & 1) * 64;
  const int se = tid >> 1;         // staging row (0..127), 2 threads/row
  const int sk = (tid & 1) * 32;   // k half within 64-chunk

  f32x4 acc[4][4];
#pragma unroll
  for (int mi = 0; mi < 4; mi++)
#pragma unroll
    for (int ni = 0; ni < 4; ni++) acc[mi][ni] = (f32x4){0.f, 0.f, 0.f, 0.f};

  for (int kb = 0; kb < KT; kb += 64) {
    // ---- stage m-tile ----
    if (kb < 512) {
      const int node = (kb < 256) ? sDst[se] : sSrc[se];
      const bf16_t* p = xb + (size_t)node * NC + (kb & 255) + sk;
      bf16x8* dst = (bf16x8*)&sM[se * 72 + sk];
      dst[0] = *(const bf16x8*)(p);
      dst[1] = *(const bf16x8*)(p + 8);
      dst[2] = *(const bf16x8*)(p + 16);
      dst[3] = *(const bf16x8*)(p + 24);
    } else {
      const float* pf = ea + (size_t)(e0 + se) * NC + (kb - 512) + sk;
      f32x4 f[8];
#pragma unroll
      for (int i = 0; i < 8; i++) f[i] = *(const f32x4*)(pf + i * 4);
      bf16x8* dst = (bf16x8*)&sM[se * 72 + sk];
#pragma unroll
      for (int i = 0; i < 4; i++) {
        bf16x8 v;
#pragma unroll
        for (int j = 0; j < 4; j++) {
          v[j]     = (bf16_t)f[2 * i][j];
          v[4 + j] = (bf16_t)f[2 * i + 1][j];
        }
        dst[i] = v;
      }
    }
    // ---- stage W-tile (already bf16, [col][k]) ----
    {
      const bf16_t* pw = w1t + (size_t)(n0 + se) * KT + kb + sk;
      bf16x8* dst = (bf16x8*)&sW[se * 72 + sk];
      dst[0] = *(const bf16x8*)(pw);
      dst[1] = *(const bf16x8*)(pw + 8);
      dst[2] = *(const bf16x8*)(pw + 16);
      dst[3] = *(const bf16x8*)(pw + 24);
    }
    __syncthreads();
    // ---- MFMA ----
#pragma unroll
    for (int kk = 0; kk < 2; kk++) {
      const int krd = kk * 32 + (lane >> 4) * 8;
      bf16x8 av[4], bv[4];
#pragma unroll
      for (int mi = 0; mi < 4; mi++)
        av[mi] = *(const bf16x8*)&sM[(mbase + mi * 16 + (lane & 15)) * 72 + krd];
#pragma unroll
      for (int ni = 0; ni < 4; ni++)
        bv[ni] = *(const bf16x8*)&sW[(nbase + ni * 16 + (lane & 15)) * 72 + krd];
#pragma unroll
      for (int mi = 0; mi < 4; mi++)
#pragma unroll
        for (int ni = 0; ni < 4; ni++)
          acc[mi][ni] = __builtin_amdgcn_mfma_f32_16x16x32_bf16(av[mi], bv[ni], acc[mi][ni], 0, 0, 0);
    }
    __syncthreads();
  }

  // ---- epilogue: relu(acc + b1) -> atomic scatter into agg[dst] ----
  float b1v[4];
#pragma unroll
  for (int ni = 0; ni < 4; ni++) b1v[ni] = b1[n0 + nbase + ni * 16 + (lane & 15)];
#pragma unroll
  for (int mi = 0; mi < 4; mi++) {
    const int rb = mbase + mi * 16 + (lane >> 4) * 4;
#pragma unroll
    for (int q = 0; q < 4; q++) {
      const int d = sDst[rb + q];
      float* arow = agg + (size_t)d * OC + n0 + nbase + (lane & 15);
#pragma unroll
      for (int ni = 0; ni < 4; ni++) {
        const float v = acc[mi][ni][q] + b1v[ni];
        if (v > 0.0f) atomicAdd(arow + ni * 16, v);  // relu; skip zero adds
      }
    }
  }
}

// ---------------------------------------------------------------------------
// Node GEMM: out = agg @ W2 + deg * b2   (10000x512 @ 512x512)
// ---------------------------------------------------------------------------
__global__ __launch_bounds__(256) void k_node_gemm(
    const float*  __restrict__ agg,
    const bf16_t* __restrict__ w2t,    // [OC][OC] transposed
    const float*  __restrict__ b2,
    const int*    __restrict__ deg,
    float*        __restrict__ out) {
  __shared__ bf16_t sM[128 * 72];
  __shared__ bf16_t sW[128 * 72];

  const int tid  = threadIdx.x;
  const int bid  = blockIdx.x;
  const int cb   = bid & 3;
  const int rblk = bid >> 2;
  const int r0   = rblk * 128;
  const int n0   = cb * 128;

  const int lane  = tid & 63, wid = tid >> 6;
  const int mbase = (wid >> 1) * 64, nbase = (wid & 1) * 64;
  const int se = tid >> 1;
  const int sk = (tid & 1) * 32;
  const int arow  = r0 + se;
  const bool rowok = arow < NN;

  f32x4 acc[4][4];
#pragma unroll
  for (int mi = 0; mi < 4; mi++)
#pragma unroll
    for (int ni = 0; ni < 4; ni++) acc[mi][ni] = (f32x4){0.f, 0.f, 0.f, 0.f};

  for (int kb = 0; kb < OC; kb += 64) {
    {
      bf16x8* dst = (bf16x8*)&sM[se * 72 + sk];
      if (rowok) {
        const float* pf = agg + (size_t)arow * OC + kb + sk;
        f32x4 f[8];
#pragma unroll
        for (int i = 0; i < 8; i++) f[i] = *(const f32x4*)(pf + i * 4);
#pragma unroll
        for (int i = 0; i < 4; i++) {
          bf16x8 v;
#pragma unroll
          for (int j = 0; j < 4; j++) {
            v[j]     = (bf16_t)f[2 * i][j];
            v[4 + j] = (bf16_t)f[2 * i + 1][j];
          }
          dst[i] = v;
        }
      } else {
        bf16x8 z = {};
        dst[0] = z; dst[1] = z; dst[2] = z; dst[3] = z;
      }
    }
    {
      const bf16_t* pw = w2t + (size_t)(n0 + se) * OC + kb + sk;
      bf16x8* dst = (bf16x8*)&sW[se * 72 + sk];
      dst[0] = *(const bf16x8*)(pw);
      dst[1] = *(const bf16x8*)(pw + 8);
      dst[2] = *(const bf16x8*)(pw + 16);
      dst[3] = *(const bf16x8*)(pw + 24);
    }
    __syncthreads();
#pragma unroll
    for (int kk = 0; kk < 2; kk++) {
      const int krd = kk * 32 + (lane >> 4) * 8;
      bf16x8 av[4], bv[4];
#pragma unroll
      for (int mi = 0; mi < 4; mi++)
        av[mi] = *(const bf16x8*)&sM[(mbase + mi * 16 + (lane & 15)) * 72 + krd];
#pragma unroll
      for (int ni = 0; ni < 4; ni++)
        bv[ni] = *(const bf16x8*)&sW[(nbase + ni * 16 + (lane & 15)) * 72 + krd];
#pragma unroll
      for (int mi = 0; mi < 4; mi++)
#pragma unroll
        for (int ni = 0; ni < 4; ni++)
          acc[mi][ni] = __builtin_amdgcn_mfma_f32_16x16x32_bf16(av[mi], bv[ni], acc[mi][ni], 0, 0, 0);
    }
    __syncthreads();
  }

  float b2v[4];
#pragma unroll
  for (int ni = 0; ni < 4; ni++) b2v[ni] = b2[n0 + nbase + ni * 16 + (lane & 15)];
#pragma unroll
  for (int mi = 0; mi < 4; mi++) {
    const int rb = mbase + mi * 16 + (lane >> 4) * 4;
#pragma unroll
    for (int q = 0; q < 4; q++) {
      const int row = r0 + rb + q;
      if (row < NN) {
        const float dg = (float)deg[row];
        float* orow = out + (size_t)row * OC + n0 + nbase + (lane & 15);
#pragma unroll
        for (int ni = 0; ni < 4; ni++)
          orow[ni * 16] = acc[mi][ni][q] + b2v[ni] * dg;
      }
    }
  }
}

// ---------------------------------------------------------------------------
// BatchNorm: stats (sum, sumsq per channel), finalize, apply(+relu) in-place.
// ---------------------------------------------------------------------------
__global__ void k_bn_stats(const float* __restrict__ out, float* __restrict__ sums) {
  const int c = threadIdx.x;  // 256 threads -> channels c and c+256
  float s1 = 0.f, q1 = 0.f, s2 = 0.f, q2 = 0.f;
  for (int n = blockIdx.x; n < NN; n += gridDim.x) {
    const float* row = out + (size_t)n * OC;
    const float v1 = row[c], v2 = row[c + 256];
    s1 += v1; q1 += v1 * v1;
    s2 += v2; q2 += v2 * v2;
  }
  atomicAdd(&sums[c], s1);        atomicAdd(&sums[OC + c], q1);
  atomicAdd(&sums[c + 256], s2);  atomicAdd(&sums[OC + c + 256], q2);
}

__global__ void k_bn_finalize(const float* __restrict__ sums,
                              const float* __restrict__ gamma,
                              const float* __restrict__ beta,
                              float* __restrict__ scale,
                              float* __restrict__ shift) {
  const int c = threadIdx.x;
  const float mean = sums[c] * (1.0f / NN);
  const float var  = sums[OC + c] * (1.0f / NN) - mean * mean;
  const float r    = rsqrtf(var + 1e-5f);
  const float sc   = r * gamma[c];
  scale[c] = sc;
  shift[c] = beta[c] - mean * sc;
}

__global__ void k_bn_apply(float* __restrict__ out,
                           const float* __restrict__ scale,
                           const float* __restrict__ shift) {
  const int i = blockIdx.x * blockDim.x + threadIdx.x;  // float4 index
  f32x4 v = *((const f32x4*)out + i);
  const int c = (i & 127) << 2;
  f32x4 r;
#pragma unroll
  for (int j = 0; j < 4; j++) r[j] = fmaxf(v[j] * scale[c + j] + shift[c + j], 0.0f);
  *((f32x4*)out + i) = r;
}

// ---------------------------------------------------------------------------
extern "C" void kernel_launch(void* const* d_in, const int* in_sizes, int n_in,
                              void* d_out, int out_size, void* d_ws, size_t ws_size,
                              hipStream_t stream) {
  const float* x     = (const float*)d_in[0];
  const int*   ei    = (const int*)d_in[1];   // [2][NE] int32 (harness-normalized)
  const float* ea    = (const float*)d_in[2];
  const float* W1    = (const float*)d_in[3];
  const float* b1    = (const float*)d_in[4];
  const float* W2    = (const float*)d_in[5];
  const float* b2    = (const float*)d_in[6];
  const float* gamma = (const float*)d_in[7];
  const float* beta  = (const float*)d_in[8];
  float* out = (float*)d_out;

  char* ws = (char*)d_ws;
  float*  agg   = (float*)(ws);                    // 20,480,000 B
  bf16_t* xb    = (bf16_t*)(ws + 20480000);        //  5,120,000 B
  bf16_t* w1t   = (bf16_t*)(ws + 25600000);        //    786,432 B
  bf16_t* w2t   = (bf16_t*)(ws + 26386432);        //    524,288 B
  int*    deg   = (int*)(ws + 26910720);           //     40,000 B
  float*  sums  = (float*)(ws + 26950720);         //      4,096 B
  float*  scale = (float*)(ws + 26954816);         //      2,048 B
  float*  shift = (float*)(ws + 26956864);         //      2,048 B

  const int* srcIdx = ei;        // edge_index[0]
  const int* dstIdx = ei + NE;   // edge_index[1]

  k_prep<<<4096, 256, 0, stream>>>(x, W1, W2, xb, w1t, w2t, agg, deg, sums);
  k_deg<<<(NE + 255) / 256, 256, 0, stream>>>(dstIdx, deg);
  k_edge_gemm<<<(NE / 128) * 4, 256, 0, stream>>>(xb, ea, w1t, b1, srcIdx, dstIdx, agg);
  k_node_gemm<<<((NN + 127) / 128) * 4, 256, 0, stream>>>(agg, w2t, b2, deg, out);
  k_bn_stats<<<256, 256, 0, stream>>>(out, sums);
  k_bn_finalize<<<1, 512, 0, stream>>>(sums, gamma, beta, scale, shift);
  k_bn_apply<<<(NN * OC / 4 + 255) / 256, 256, 0, stream>>>(out, scale, shift);
}

// Round 2
// 643.788 us; speedup vs baseline: 1.1804x; 1.1804x over previous
//
#include <hip/hip_runtime.h>
#include <hip/hip_bf16.h>
#include <cstdint>

// Problem constants (fixed by the reference)
#define NN 10000      // nodes
#define NE 320000     // edges
#define NC 256        // node channels
#define OC 512        // out channels
#define KT 768        // 2*NC + 256 (edge attr)

typedef __bf16 bf16_t;
typedef bf16_t bf16x8 __attribute__((ext_vector_type(8)));
typedef float  f32x4  __attribute__((ext_vector_type(4)));

// ---------------------------------------------------------------------------
// Prep: zero agg/deg/cursor/sums, convert x -> bf16, build W1' and W2
// transposed [n][k] bf16.  W1' folds the (x_j - x_i) term: W1'a = W1a - W1b.
// ---------------------------------------------------------------------------
__global__ void k_prep(const float* __restrict__ x,
                       const float* __restrict__ W1,
                       const float* __restrict__ W2,
                       bf16_t* __restrict__ xb,
                       bf16_t* __restrict__ w1t,
                       bf16_t* __restrict__ w2t,
                       float* __restrict__ agg,
                       int* __restrict__ deg,
                       int* __restrict__ cursor,
                       float* __restrict__ sums) {
  const int stride = gridDim.x * blockDim.x;
  for (int i = blockIdx.x * blockDim.x + threadIdx.x; i < NN * OC; i += stride) {
    agg[i] = 0.0f;
    if (i < NN * NC) xb[i] = (bf16_t)x[i];
    if (i < OC * KT) {
      const int n = i / KT, k = i - n * KT;
      float w = W1[(size_t)k * OC + n];
      if (k < NC) w = w - W1[(size_t)(k + NC) * OC + n];  // W1a - W1b
      w1t[i] = (bf16_t)w;
    }
    if (i < OC * OC) {
      const int n = i >> 9, k = i & 511;
      w2t[i] = (bf16_t)W2[(size_t)k * OC + n];
    }
    if (i < NN) { deg[i] = 0; cursor[i] = 0; }
    if (i < 1024) sums[i] = 0.0f;
  }
}

__global__ void k_deg(const int* __restrict__ dstIdx, int* __restrict__ deg) {
  const int i = blockIdx.x * blockDim.x + threadIdx.x;
  if (i < NE) atomicAdd(&deg[dstIdx[i]], 1);
}

// Single-block exclusive prefix sum over NN bins.
__global__ void k_scan(const int* __restrict__ deg, int* __restrict__ offs) {
  __shared__ int carry;
  __shared__ int wsum[4];
  if (threadIdx.x == 0) carry = 0;
  __syncthreads();
  const int lane = threadIdx.x & 63, w = threadIdx.x >> 6;
  for (int base = 0; base < NN; base += 256) {
    const int i = base + threadIdx.x;
    const int v = (i < NN) ? deg[i] : 0;
    int s = v;
#pragma unroll
    for (int d = 1; d < 64; d <<= 1) { int t = __shfl_up(s, d); if (lane >= d) s += t; }
    if (lane == 63) wsum[w] = s;
    __syncthreads();
    int woff = 0;
    for (int j = 0; j < w; j++) woff += wsum[j];
    const int incl = s + woff + carry;
    if (i < NN) offs[i] = incl - v;  // exclusive
    __syncthreads();
    if (threadIdx.x == 255) carry = incl;
    __syncthreads();
  }
}

// Counting-sort scatter: edges grouped by dst.
__global__ void k_scatter(const int* __restrict__ srcIdx, const int* __restrict__ dstIdx,
                          const int* __restrict__ offs, int* __restrict__ cursor,
                          int* __restrict__ eperm, int* __restrict__ sdst,
                          int* __restrict__ ssrc) {
  const int e = blockIdx.x * blockDim.x + threadIdx.x;
  if (e < NE) {
    const int d = dstIdx[e];
    const int pos = offs[d] + atomicAdd(&cursor[d], 1);
    eperm[pos] = e;
    sdst[pos] = d;
    ssrc[pos] = srcIdx[e];
  }
}

// ---------------------------------------------------------------------------
// Edge GEMM over dst-sorted edges: per 128-edge x 128-col tile, K=768.
// m' = [x_i | x_j | ea] (pure gathers thanks to W1' folding).
// Epilogue: relu(acc + b1), segmented-reduced over sorted dst runs in
// registers (quad walk + guarded shfl merge across 16-row stripes), then
// one atomicAdd per (run, col).
// ---------------------------------------------------------------------------
__global__ __launch_bounds__(256) void k_edge_gemm(
    const bf16_t* __restrict__ xb,     // [NN][NC] bf16
    const float*  __restrict__ ea,     // [NE][NC] f32
    const bf16_t* __restrict__ w1t,    // [OC][KT] bf16 (transposed W1')
    const float*  __restrict__ b1,
    const int*    __restrict__ eperm,  // sorted -> original edge
    const int*    __restrict__ sdst,   // sorted dst (non-decreasing)
    const int*    __restrict__ ssrc,   // src in sorted order
    float*        __restrict__ agg) {  // [NN][OC] f32
  __shared__ bf16_t sM[128 * 72];      // [edge][k] pad 72
  __shared__ bf16_t sW[128 * 72];      // [col][k]  pad 72
  __shared__ int sDst[128];
  __shared__ int sSrc[128];
  __shared__ int sE[128];

  const int tid  = threadIdx.x;
  const int bid  = blockIdx.x;
  const int cb   = bid & 3;        // col-block fastest: edge tile reused via L2
  const int eblk = bid >> 2;
  const int e0   = eblk * 128;
  const int n0   = cb * 128;

  if (tid < 128) {
    sDst[tid] = sdst[e0 + tid];
    sSrc[tid] = ssrc[e0 + tid];
    sE[tid]   = eperm[e0 + tid];
  }
  __syncthreads();

  const int lane  = tid & 63, wid = tid >> 6;
  const int mbase = (wid >> 1) * 64, nbase = (wid & 1) * 64;
  const int se = tid >> 1;         // staging row (0..127), 2 threads/row
  const int sk = (tid & 1) * 32;   // k half within 64-chunk

  f32x4 acc[4][4];
#pragma unroll
  for (int mi = 0; mi < 4; mi++)
#pragma unroll
    for (int ni = 0; ni < 4; ni++) acc[mi][ni] = (f32x4){0.f, 0.f, 0.f, 0.f};

  for (int kb = 0; kb < KT; kb += 64) {
    // ---- stage m-tile ----
    if (kb < 512) {
      const int node = (kb < 256) ? sDst[se] : sSrc[se];
      const bf16_t* p = xb + (size_t)node * NC + (kb & 255) + sk;
      bf16x8* dst = (bf16x8*)&sM[se * 72 + sk];
      dst[0] = *(const bf16x8*)(p);
      dst[1] = *(const bf16x8*)(p + 8);
      dst[2] = *(const bf16x8*)(p + 16);
      dst[3] = *(const bf16x8*)(p + 24);
    } else {
      const float* pf = ea + (size_t)sE[se] * NC + (kb - 512) + sk;
      f32x4 f[8];
#pragma unroll
      for (int i = 0; i < 8; i++) f[i] = *(const f32x4*)(pf + i * 4);
      bf16x8* dst = (bf16x8*)&sM[se * 72 + sk];
#pragma unroll
      for (int i = 0; i < 4; i++) {
        bf16x8 v;
#pragma unroll
        for (int j = 0; j < 4; j++) {
          v[j]     = (bf16_t)f[2 * i][j];
          v[4 + j] = (bf16_t)f[2 * i + 1][j];
        }
        dst[i] = v;
      }
    }
    // ---- stage W-tile (already bf16, [col][k]) ----
    {
      const bf16_t* pw = w1t + (size_t)(n0 + se) * KT + kb + sk;
      bf16x8* dst = (bf16x8*)&sW[se * 72 + sk];
      dst[0] = *(const bf16x8*)(pw);
      dst[1] = *(const bf16x8*)(pw + 8);
      dst[2] = *(const bf16x8*)(pw + 16);
      dst[3] = *(const bf16x8*)(pw + 24);
    }
    __syncthreads();
    // ---- MFMA ----
#pragma unroll
    for (int kk = 0; kk < 2; kk++) {
      const int krd = kk * 32 + (lane >> 4) * 8;
      bf16x8 av[4], bv[4];
#pragma unroll
      for (int mi = 0; mi < 4; mi++)
        av[mi] = *(const bf16x8*)&sM[(mbase + mi * 16 + (lane & 15)) * 72 + krd];
#pragma unroll
      for (int ni = 0; ni < 4; ni++)
        bv[ni] = *(const bf16x8*)&sW[(nbase + ni * 16 + (lane & 15)) * 72 + krd];
#pragma unroll
      for (int mi = 0; mi < 4; mi++)
#pragma unroll
        for (int ni = 0; ni < 4; ni++)
          acc[mi][ni] = __builtin_amdgcn_mfma_f32_16x16x32_bf16(av[mi], bv[ni], acc[mi][ni], 0, 0, 0);
    }
    __syncthreads();
  }

  // ---- epilogue: relu(acc + b1) -> segmented reduce over sorted dst ----
  float b1v[4];
#pragma unroll
  for (int ni = 0; ni < 4; ni++) b1v[ni] = b1[n0 + nbase + ni * 16 + (lane & 15)];

  const int g = lane >> 4;
#pragma unroll
  for (int mi = 0; mi < 4; mi++) {
    const int rbase = mbase + mi * 16 + g * 4;   // first sorted row of my quad
    const int d0 = sDst[rbase],     d1 = sDst[rbase + 1];
    const int d2 = sDst[rbase + 2], d3 = sDst[rbase + 3];
    const int headId = d0, tailId = d3;
    const bool b1q = (d1 != d0), b2q = (d2 != d1), b3q = (d3 != d2);
    const bool seen = b1q | b2q | b3q;           // quad has a boundary
    // tail ids of groups 0..2 (uniform within group; read from matching col lane)
    bool match[3];
#pragma unroll
    for (int j = 0; j < 3; j++) {
      const int tIdj = __shfl(tailId, (lane & 15) | (j << 4));
      match[j] = (j < g) && (tIdj == headId);
    }
    const int nextHead = __shfl(headId, (lane + 16) & 63);
    const bool endsHere = (g == 3) || (nextHead != tailId);

#pragma unroll
    for (int ni = 0; ni < 4; ni++) {
      const int col = n0 + nbase + ni * 16 + (lane & 15);
      const float v0 = fmaxf(acc[mi][ni][0] + b1v[ni], 0.f);
      const float v1 = fmaxf(acc[mi][ni][1] + b1v[ni], 0.f);
      const float v2 = fmaxf(acc[mi][ni][2] + b1v[ni], 0.f);
      const float v3 = fmaxf(acc[mi][ni][3] + b1v[ni], 0.f);
      // quad walk: head run, interior runs (flushed), tail run
      float head = 0.f, run = v0;
      bool first = true;
      if (b1q) { head = run; first = false; run = v1; } else run += v1;
      if (b2q) {
        if (first) { head = run; first = false; }
        else if (run != 0.f) atomicAdd(agg + (size_t)d1 * OC + col, run);
        run = v2;
      } else run += v2;
      if (b3q) {
        if (first) { head = run; first = false; }
        else if (run != 0.f) atomicAdd(agg + (size_t)d2 * OC + col, run);
        run = v3;
      } else run += v3;
      const float tailSum = run;
      // incoming prefix: matching tails of earlier groups in this 16-row stripe
      float inc = 0.f;
#pragma unroll
      for (int j = 0; j < 3; j++) {
        const float ts = __shfl(tailSum, (lane & 15) | (j << 4));
        if (match[j]) inc += ts;
      }
      if (seen) {
        const float h = head + inc;
        if (h != 0.f) atomicAdd(agg + (size_t)headId * OC + col, h);
      }
      if (endsHere) {
        const float t = tailSum + (seen ? 0.f : inc);
        if (t != 0.f) atomicAdd(agg + (size_t)tailId * OC + col, t);
      }
    }
  }
}

// ---------------------------------------------------------------------------
// Node GEMM: out = agg @ W2 + deg * b2   (10000x512 @ 512x512)
// ---------------------------------------------------------------------------
__global__ __launch_bounds__(256) void k_node_gemm(
    const float*  __restrict__ agg,
    const bf16_t* __restrict__ w2t,    // [OC][OC] transposed
    const float*  __restrict__ b2,
    const int*    __restrict__ deg,
    float*        __restrict__ out) {
  __shared__ bf16_t sM[128 * 72];
  __shared__ bf16_t sW[128 * 72];

  const int tid  = threadIdx.x;
  const int bid  = blockIdx.x;
  const int cb   = bid & 3;
  const int rblk = bid >> 2;
  const int r0   = rblk * 128;
  const int n0   = cb * 128;

  const int lane  = tid & 63, wid = tid >> 6;
  const int mbase = (wid >> 1) * 64, nbase = (wid & 1) * 64;
  const int se = tid >> 1;
  const int sk = (tid & 1) * 32;
  const int arow  = r0 + se;
  const bool rowok = arow < NN;

  f32x4 acc[4][4];
#pragma unroll
  for (int mi = 0; mi < 4; mi++)
#pragma unroll
    for (int ni = 0; ni < 4; ni++) acc[mi][ni] = (f32x4){0.f, 0.f, 0.f, 0.f};

  for (int kb = 0; kb < OC; kb += 64) {
    {
      bf16x8* dst = (bf16x8*)&sM[se * 72 + sk];
      if (rowok) {
        const float* pf = agg + (size_t)arow * OC + kb + sk;
        f32x4 f[8];
#pragma unroll
        for (int i = 0; i < 8; i++) f[i] = *(const f32x4*)(pf + i * 4);
#pragma unroll
        for (int i = 0; i < 4; i++) {
          bf16x8 v;
#pragma unroll
          for (int j = 0; j < 4; j++) {
            v[j]     = (bf16_t)f[2 * i][j];
            v[4 + j] = (bf16_t)f[2 * i + 1][j];
          }
          dst[i] = v;
        }
      } else {
        bf16x8 z = {};
        dst[0] = z; dst[1] = z; dst[2] = z; dst[3] = z;
      }
    }
    {
      const bf16_t* pw = w2t + (size_t)(n0 + se) * OC + kb + sk;
      bf16x8* dst = (bf16x8*)&sW[se * 72 + sk];
      dst[0] = *(const bf16x8*)(pw);
      dst[1] = *(const bf16x8*)(pw + 8);
      dst[2] = *(const bf16x8*)(pw + 16);
      dst[3] = *(const bf16x8*)(pw + 24);
    }
    __syncthreads();
#pragma unroll
    for (int kk = 0; kk < 2; kk++) {
      const int krd = kk * 32 + (lane >> 4) * 8;
      bf16x8 av[4], bv[4];
#pragma unroll
      for (int mi = 0; mi < 4; mi++)
        av[mi] = *(const bf16x8*)&sM[(mbase + mi * 16 + (lane & 15)) * 72 + krd];
#pragma unroll
      for (int ni = 0; ni < 4; ni++)
        bv[ni] = *(const bf16x8*)&sW[(nbase + ni * 16 + (lane & 15)) * 72 + krd];
#pragma unroll
      for (int mi = 0; mi < 4; mi++)
#pragma unroll
        for (int ni = 0; ni < 4; ni++)
          acc[mi][ni] = __builtin_amdgcn_mfma_f32_16x16x32_bf16(av[mi], bv[ni], acc[mi][ni], 0, 0, 0);
    }
    __syncthreads();
  }

  float b2v[4];
#pragma unroll
  for (int ni = 0; ni < 4; ni++) b2v[ni] = b2[n0 + nbase + ni * 16 + (lane & 15)];
#pragma unroll
  for (int mi = 0; mi < 4; mi++) {
    const int rb = mbase + mi * 16 + (lane >> 4) * 4;
#pragma unroll
    for (int q = 0; q < 4; q++) {
      const int row = r0 + rb + q;
      if (row < NN) {
        const float dg = (float)deg[row];
        float* orow = out + (size_t)row * OC + n0 + nbase + (lane & 15);
#pragma unroll
        for (int ni = 0; ni < 4; ni++)
          orow[ni * 16] = acc[mi][ni][q] + b2v[ni] * dg;
      }
    }
  }
}

// ---------------------------------------------------------------------------
// BatchNorm: stats (sum, sumsq per channel), finalize, apply(+relu) in-place.
// ---------------------------------------------------------------------------
__global__ void k_bn_stats(const float* __restrict__ out, float* __restrict__ sums) {
  const int c = threadIdx.x;  // 256 threads -> channels c and c+256
  float s1 = 0.f, q1 = 0.f, s2 = 0.f, q2 = 0.f;
  for (int n = blockIdx.x; n < NN; n += gridDim.x) {
    const float* row = out + (size_t)n * OC;
    const float v1 = row[c], v2 = row[c + 256];
    s1 += v1; q1 += v1 * v1;
    s2 += v2; q2 += v2 * v2;
  }
  atomicAdd(&sums[c], s1);        atomicAdd(&sums[OC + c], q1);
  atomicAdd(&sums[c + 256], s2);  atomicAdd(&sums[OC + c + 256], q2);
}

__global__ void k_bn_finalize(const float* __restrict__ sums,
                              const float* __restrict__ gamma,
                              const float* __restrict__ beta,
                              float* __restrict__ scale,
                              float* __restrict__ shift) {
  const int c = threadIdx.x;
  const float mean = sums[c] * (1.0f / NN);
  const float var  = sums[OC + c] * (1.0f / NN) - mean * mean;
  const float r    = rsqrtf(var + 1e-5f);
  const float sc   = r * gamma[c];
  scale[c] = sc;
  shift[c] = beta[c] - mean * sc;
}

__global__ void k_bn_apply(float* __restrict__ out,
                           const float* __restrict__ scale,
                           const float* __restrict__ shift) {
  const int i = blockIdx.x * blockDim.x + threadIdx.x;  // float4 index
  f32x4 v = *((const f32x4*)out + i);
  const int c = (i & 127) << 2;
  f32x4 r;
#pragma unroll
  for (int j = 0; j < 4; j++) r[j] = fmaxf(v[j] * scale[c + j] + shift[c + j], 0.0f);
  *((f32x4*)out + i) = r;
}

// ---------------------------------------------------------------------------
extern "C" void kernel_launch(void* const* d_in, const int* in_sizes, int n_in,
                              void* d_out, int out_size, void* d_ws, size_t ws_size,
                              hipStream_t stream) {
  const float* x     = (const float*)d_in[0];
  const int*   ei    = (const int*)d_in[1];   // [2][NE] int32 (harness-normalized)
  const float* ea    = (const float*)d_in[2];
  const float* W1    = (const float*)d_in[3];
  const float* b1    = (const float*)d_in[4];
  const float* W2    = (const float*)d_in[5];
  const float* b2    = (const float*)d_in[6];
  const float* gamma = (const float*)d_in[7];
  const float* beta  = (const float*)d_in[8];
  float* out = (float*)d_out;

  char* ws = (char*)d_ws;
  float*  agg    = (float*)(ws);                    // 20,480,000 B
  bf16_t* xb     = (bf16_t*)(ws + 20480000);        //  5,120,000 B
  bf16_t* w1t    = (bf16_t*)(ws + 25600000);        //    786,432 B
  bf16_t* w2t    = (bf16_t*)(ws + 26386432);        //    524,288 B
  int*    deg    = (int*)(ws + 26910720);           //     40,000 B
  int*    offs   = (int*)(ws + 26950720);           //     40,000 B
  int*    cursor = (int*)(ws + 26990720);           //     40,000 B
  float*  sums   = (float*)(ws + 27030720);         //      4,096 B
  float*  scale  = (float*)(ws + 27034816);         //      2,048 B
  float*  shift  = (float*)(ws + 27036864);         //      2,048 B
  int*    eperm  = (int*)(ws + 27038912);           //  1,280,000 B
  int*    sdst   = (int*)(ws + 28318912);           //  1,280,000 B
  int*    ssrc   = (int*)(ws + 29598912);           //  1,280,000 B

  const int* srcIdx = ei;        // edge_index[0]
  const int* dstIdx = ei + NE;   // edge_index[1]

  k_prep<<<4096, 256, 0, stream>>>(x, W1, W2, xb, w1t, w2t, agg, deg, cursor, sums);
  k_deg<<<(NE + 255) / 256, 256, 0, stream>>>(dstIdx, deg);
  k_scan<<<1, 256, 0, stream>>>(deg, offs);
  k_scatter<<<(NE + 255) / 256, 256, 0, stream>>>(srcIdx, dstIdx, offs, cursor,
                                                  eperm, sdst, ssrc);
  k_edge_gemm<<<(NE / 128) * 4, 256, 0, stream>>>(xb, ea, w1t, b1, eperm, sdst, ssrc, agg);
  k_node_gemm<<<((NN + 127) / 128) * 4, 256, 0, stream>>>(agg, w2t, b2, deg, out);
  k_bn_stats<<<256, 256, 0, stream>>>(out, sums);
  k_bn_finalize<<<1, 512, 0, stream>>>(sums, gamma, beta, scale, shift);
  k_bn_apply<<<(NN * OC / 4 + 255) / 256, 256, 0, stream>>>(out, scale, shift);
}

// Round 3
// 642.903 us; speedup vs baseline: 1.1820x; 1.0014x over previous
//
#include <hip/hip_runtime.h>
#include <hip/hip_bf16.h>
#include <cstdint>

// Problem constants (fixed by the reference)
#define NN 10000      // nodes
#define NE 320000     // edges
#define NC 256        // node channels
#define OC 512        // out channels
#define KT 768        // 2*NC + 256 (edge attr)

typedef __bf16 bf16_t;
typedef bf16_t bf16x8 __attribute__((ext_vector_type(8)));
typedef float  f32x4  __attribute__((ext_vector_type(4)));

// ---------------------------------------------------------------------------
// Prep: zero agg/deg/cursor/sums, convert x -> bf16, build W1' and W2
// transposed [n][k] bf16.  W1' folds the (x_j - x_i) term: W1'a = W1a - W1b.
// ---------------------------------------------------------------------------
__global__ void k_prep(const float* __restrict__ x,
                       const float* __restrict__ W1,
                       const float* __restrict__ W2,
                       bf16_t* __restrict__ xb,
                       bf16_t* __restrict__ w1t,
                       bf16_t* __restrict__ w2t,
                       float* __restrict__ agg,
                       int* __restrict__ deg,
                       int* __restrict__ cursor,
                       float* __restrict__ sums) {
  const int stride = gridDim.x * blockDim.x;
  for (int i = blockIdx.x * blockDim.x + threadIdx.x; i < NN * OC; i += stride) {
    agg[i] = 0.0f;
    if (i < NN * NC) xb[i] = (bf16_t)x[i];
    if (i < OC * KT) {
      const int n = i / KT, k = i - n * KT;
      float w = W1[(size_t)k * OC + n];
      if (k < NC) w = w - W1[(size_t)(k + NC) * OC + n];  // W1a - W1b
      w1t[i] = (bf16_t)w;
    }
    if (i < OC * OC) {
      const int n = i >> 9, k = i & 511;
      w2t[i] = (bf16_t)W2[(size_t)k * OC + n];
    }
    if (i < NN) { deg[i] = 0; cursor[i] = 0; }
    if (i < 1024) sums[i] = 0.0f;
  }
}

__global__ void k_deg(const int* __restrict__ dstIdx, int* __restrict__ deg) {
  const int i = blockIdx.x * blockDim.x + threadIdx.x;
  if (i < NE) atomicAdd(&deg[dstIdx[i]], 1);
}

// Single-block exclusive prefix sum over NN bins.
__global__ void k_scan(const int* __restrict__ deg, int* __restrict__ offs) {
  __shared__ int carry;
  __shared__ int wsum[4];
  if (threadIdx.x == 0) carry = 0;
  __syncthreads();
  const int lane = threadIdx.x & 63, w = threadIdx.x >> 6;
  for (int base = 0; base < NN; base += 256) {
    const int i = base + threadIdx.x;
    const int v = (i < NN) ? deg[i] : 0;
    int s = v;
#pragma unroll
    for (int d = 1; d < 64; d <<= 1) { int t = __shfl_up(s, d); if (lane >= d) s += t; }
    if (lane == 63) wsum[w] = s;
    __syncthreads();
    int woff = 0;
    for (int j = 0; j < w; j++) woff += wsum[j];
    const int incl = s + woff + carry;
    if (i < NN) offs[i] = incl - v;  // exclusive
    __syncthreads();
    if (threadIdx.x == 255) carry = incl;
    __syncthreads();
  }
}

// Counting-sort scatter: edges grouped by dst.
__global__ void k_scatter(const int* __restrict__ srcIdx, const int* __restrict__ dstIdx,
                          const int* __restrict__ offs, int* __restrict__ cursor,
                          int* __restrict__ eperm, int* __restrict__ sdst,
                          int* __restrict__ ssrc) {
  const int e = blockIdx.x * blockDim.x + threadIdx.x;
  if (e < NE) {
    const int d = dstIdx[e];
    const int pos = offs[d] + atomicAdd(&cursor[d], 1);
    eperm[pos] = e;
    sdst[pos] = d;
    ssrc[pos] = srcIdx[e];
  }
}

// ---------------------------------------------------------------------------
// Edge GEMM over dst-sorted edges: per 128-edge x 128-col tile, K=768.
// m' = [x_i | x_j | ea] (pure gathers thanks to W1' folding).
// Epilogue: relu(acc + b1), segmented-reduced over sorted dst runs in
// registers (quad walk + guarded shfl merge across 16-row stripes), then
// one atomicAdd per (run, col).
// ---------------------------------------------------------------------------
__global__ __launch_bounds__(256) void k_edge_gemm(
    const bf16_t* __restrict__ xb,     // [NN][NC] bf16
    const float*  __restrict__ ea,     // [NE][NC] f32
    const bf16_t* __restrict__ w1t,    // [OC][KT] bf16 (transposed W1')
    const float*  __restrict__ b1,
    const int*    __restrict__ eperm,  // sorted -> original edge
    const int*    __restrict__ sdst,   // sorted dst (non-decreasing)
    const int*    __restrict__ ssrc,   // src in sorted order
    float*        __restrict__ agg) {  // [NN][OC] f32
  __shared__ bf16_t sM[128 * 72];      // [edge][k] pad 72
  __shared__ bf16_t sW[128 * 72];      // [col][k]  pad 72
  __shared__ int sDst[128];
  __shared__ int sSrc[128];
  __shared__ int sE[128];

  const int tid  = threadIdx.x;
  const int bid  = blockIdx.x;
  const int cb   = bid & 3;        // col-block fastest: edge tile reused via L2
  const int eblk = bid >> 2;
  const int e0   = eblk * 128;
  const int n0   = cb * 128;

  if (tid < 128) {
    sDst[tid] = sdst[e0 + tid];
    sSrc[tid] = ssrc[e0 + tid];
    sE[tid]   = eperm[e0 + tid];
  }
  __syncthreads();

  const int lane  = tid & 63, wid = tid >> 6;
  const int mbase = (wid >> 1) * 64, nbase = (wid & 1) * 64;
  const int se = tid >> 1;         // staging row (0..127), 2 threads/row
  const int sk = (tid & 1) * 32;   // k half within 64-chunk

  f32x4 acc[4][4];
#pragma unroll
  for (int mi = 0; mi < 4; mi++)
#pragma unroll
    for (int ni = 0; ni < 4; ni++) acc[mi][ni] = (f32x4){0.f, 0.f, 0.f, 0.f};

  for (int kb = 0; kb < KT; kb += 64) {
    // ---- stage m-tile ----
    if (kb < 512) {
      const int node = (kb < 256) ? sDst[se] : sSrc[se];
      const bf16_t* p = xb + (size_t)node * NC + (kb & 255) + sk;
      bf16x8* dst = (bf16x8*)&sM[se * 72 + sk];
      dst[0] = *(const bf16x8*)(p);
      dst[1] = *(const bf16x8*)(p + 8);
      dst[2] = *(const bf16x8*)(p + 16);
      dst[3] = *(const bf16x8*)(p + 24);
    } else {
      const float* pf = ea + (size_t)sE[se] * NC + (kb - 512) + sk;
      f32x4 f[8];
#pragma unroll
      for (int i = 0; i < 8; i++) f[i] = *(const f32x4*)(pf + i * 4);
      bf16x8* dst = (bf16x8*)&sM[se * 72 + sk];
#pragma unroll
      for (int i = 0; i < 4; i++) {
        bf16x8 v;
#pragma unroll
        for (int j = 0; j < 4; j++) {
          v[j]     = (bf16_t)f[2 * i][j];
          v[4 + j] = (bf16_t)f[2 * i + 1][j];
        }
        dst[i] = v;
      }
    }
    // ---- stage W-tile (already bf16, [col][k]) ----
    {
      const bf16_t* pw = w1t + (size_t)(n0 + se) * KT + kb + sk;
      bf16x8* dst = (bf16x8*)&sW[se * 72 + sk];
      dst[0] = *(const bf16x8*)(pw);
      dst[1] = *(const bf16x8*)(pw + 8);
      dst[2] = *(const bf16x8*)(pw + 16);
      dst[3] = *(const bf16x8*)(pw + 24);
    }
    __syncthreads();
    // ---- MFMA ----
#pragma unroll
    for (int kk = 0; kk < 2; kk++) {
      const int krd = kk * 32 + (lane >> 4) * 8;
      bf16x8 av[4], bv[4];
#pragma unroll
      for (int mi = 0; mi < 4; mi++)
        av[mi] = *(const bf16x8*)&sM[(mbase + mi * 16 + (lane & 15)) * 72 + krd];
#pragma unroll
      for (int ni = 0; ni < 4; ni++)
        bv[ni] = *(const bf16x8*)&sW[(nbase + ni * 16 + (lane & 15)) * 72 + krd];
#pragma unroll
      for (int mi = 0; mi < 4; mi++)
#pragma unroll
        for (int ni = 0; ni < 4; ni++)
          acc[mi][ni] = __builtin_amdgcn_mfma_f32_16x16x32_bf16(av[mi], bv[ni], acc[mi][ni], 0, 0, 0);
    }
    __syncthreads();
  }

  // ---- epilogue: relu(acc + b1) -> segmented reduce over sorted dst ----
  float b1v[4];
#pragma unroll
  for (int ni = 0; ni < 4; ni++) b1v[ni] = b1[n0 + nbase + ni * 16 + (lane & 15)];

  const int g = lane >> 4;
#pragma unroll
  for (int mi = 0; mi < 4; mi++) {
    const int rbase = mbase + mi * 16 + g * 4;   // first sorted row of my quad
    const int d0 = sDst[rbase],     d1 = sDst[rbase + 1];
    const int d2 = sDst[rbase + 2], d3 = sDst[rbase + 3];
    const int headId = d0, tailId = d3;
    const bool b1q = (d1 != d0), b2q = (d2 != d1), b3q = (d3 != d2);
    const bool seen = b1q | b2q | b3q;           // quad has a boundary
    // tail ids of groups 0..2 (uniform within group; read from matching col lane)
    bool match[3];
#pragma unroll
    for (int j = 0; j < 3; j++) {
      const int tIdj = __shfl(tailId, (lane & 15) | (j << 4));
      match[j] = (j < g) && (tIdj == headId);
    }
    const int nextHead = __shfl(headId, (lane + 16) & 63);
    const bool endsHere = (g == 3) || (nextHead != tailId);

#pragma unroll
    for (int ni = 0; ni < 4; ni++) {
      const int col = n0 + nbase + ni * 16 + (lane & 15);
      const float v0 = fmaxf(acc[mi][ni][0] + b1v[ni], 0.f);
      const float v1 = fmaxf(acc[mi][ni][1] + b1v[ni], 0.f);
      const float v2 = fmaxf(acc[mi][ni][2] + b1v[ni], 0.f);
      const float v3 = fmaxf(acc[mi][ni][3] + b1v[ni], 0.f);
      // quad walk: head run, interior runs (flushed), tail run
      float head = 0.f, run = v0;
      bool first = true;
      if (b1q) { head = run; first = false; run = v1; } else run += v1;
      if (b2q) {
        if (first) { head = run; first = false; }
        else if (run != 0.f) atomicAdd(agg + (size_t)d1 * OC + col, run);
        run = v2;
      } else run += v2;
      if (b3q) {
        if (first) { head = run; first = false; }
        else if (run != 0.f) atomicAdd(agg + (size_t)d2 * OC + col, run);
        run = v3;
      } else run += v3;
      const float tailSum = run;
      // incoming prefix: matching tails of earlier groups in this 16-row stripe
      float inc = 0.f;
#pragma unroll
      for (int j = 0; j < 3; j++) {
        const float ts = __shfl(tailSum, (lane & 15) | (j << 4));
        if (match[j]) inc += ts;
      }
      if (seen) {
        const float h = head + inc;
        if (h != 0.f) atomicAdd(agg + (size_t)headId * OC + col, h);
      }
      if (endsHere) {
        const float t = tailSum + (seen ? 0.f : inc);
        if (t != 0.f) atomicAdd(agg + (size_t)tailId * OC + col, t);
      }
    }
  }
}

// ---------------------------------------------------------------------------
// Node GEMM: out = agg @ W2 + deg * b2   (10000x512 @ 512x512)
// ---------------------------------------------------------------------------
__global__ __launch_bounds__(256) void k_node_gemm(
    const float*  __restrict__ agg,
    const bf16_t* __restrict__ w2t,    // [OC][OC] transposed
    const float*  __restrict__ b2,
    const int*    __restrict__ deg,
    float*        __restrict__ out) {
  __shared__ bf16_t sM[128 * 72];
  __shared__ bf16_t sW[128 * 72];

  const int tid  = threadIdx.x;
  const int bid  = blockIdx.x;
  const int cb   = bid & 3;
  const int rblk = bid >> 2;
  const int r0   = rblk * 128;
  const int n0   = cb * 128;

  const int lane  = tid & 63, wid = tid >> 6;
  const int mbase = (wid >> 1) * 64, nbase = (wid & 1) * 64;
  const int se = tid >> 1;
  const int sk = (tid & 1) * 32;
  const int arow  = r0 + se;
  const bool rowok = arow < NN;

  f32x4 acc[4][4];
#pragma unroll
  for (int mi = 0; mi < 4; mi++)
#pragma unroll
    for (int ni = 0; ni < 4; ni++) acc[mi][ni] = (f32x4){0.f, 0.f, 0.f, 0.f};

  for (int kb = 0; kb < OC; kb += 64) {
    {
      bf16x8* dst = (bf16x8*)&sM[se * 72 + sk];
      if (rowok) {
        const float* pf = agg + (size_t)arow * OC + kb + sk;
        f32x4 f[8];
#pragma unroll
        for (int i = 0; i < 8; i++) f[i] = *(const f32x4*)(pf + i * 4);
#pragma unroll
        for (int i = 0; i < 4; i++) {
          bf16x8 v;
#pragma unroll
          for (int j = 0; j < 4; j++) {
            v[j]     = (bf16_t)f[2 * i][j];
            v[4 + j] = (bf16_t)f[2 * i + 1][j];
          }
          dst[i] = v;
        }
      } else {
        bf16x8 z = {};
        dst[0] = z; dst[1] = z; dst[2] = z; dst[3] = z;
      }
    }
    {
      const bf16_t* pw = w2t + (size_t)(n0 + se) * OC + kb + sk;
      bf16x8* dst = (bf16x8*)&sW[se * 72 + sk];
      dst[0] = *(const bf16x8*)(pw);
      dst[1] = *(const bf16x8*)(pw + 8);
      dst[2] = *(const bf16x8*)(pw + 16);
      dst[3] = *(const bf16x8*)(pw + 24);
    }
    __syncthreads();
#pragma unroll
    for (int kk = 0; kk < 2; kk++) {
      const int krd = kk * 32 + (lane >> 4) * 8;
      bf16x8 av[4], bv[4];
#pragma unroll
      for (int mi = 0; mi < 4; mi++)
        av[mi] = *(const bf16x8*)&sM[(mbase + mi * 16 + (lane & 15)) * 72 + krd];
#pragma unroll
      for (int ni = 0; ni < 4; ni++)
        bv[ni] = *(const bf16x8*)&sW[(nbase + ni * 16 + (lane & 15)) * 72 + krd];
#pragma unroll
      for (int mi = 0; mi < 4; mi++)
#pragma unroll
        for (int ni = 0; ni < 4; ni++)
          acc[mi][ni] = __builtin_amdgcn_mfma_f32_16x16x32_bf16(av[mi], bv[ni], acc[mi][ni], 0, 0, 0);
    }
    __syncthreads();
  }

  float b2v[4];
#pragma unroll
  for (int ni = 0; ni < 4; ni++) b2v[ni] = b2[n0 + nbase + ni * 16 + (lane & 15)];
#pragma unroll
  for (int mi = 0; mi < 4; mi++) {
    const int rb = mbase + mi * 16 + (lane >> 4) * 4;
#pragma unroll
    for (int q = 0; q < 4; q++) {
      const int row = r0 + rb + q;
      if (row < NN) {
        const float dg = (float)deg[row];
        float* orow = out + (size_t)row * OC + n0 + nbase + (lane & 15);
#pragma unroll
        for (int ni = 0; ni < 4; ni++)
          orow[ni * 16] = acc[mi][ni][q] + b2v[ni] * dg;
      }
    }
  }
}

// ---------------------------------------------------------------------------
// BatchNorm: stats (sum, sumsq per channel), finalize, apply(+relu) in-place.
// ---------------------------------------------------------------------------
__global__ void k_bn_stats(const float* __restrict__ out, float* __restrict__ sums) {
  const int c = threadIdx.x;  // 256 threads -> channels c and c+256
  float s1 = 0.f, q1 = 0.f, s2 = 0.f, q2 = 0.f;
  for (int n = blockIdx.x; n < NN; n += gridDim.x) {
    const float* row = out + (size_t)n * OC;
    const float v1 = row[c], v2 = row[c + 256];
    s1 += v1; q1 += v1 * v1;
    s2 += v2; q2 += v2 * v2;
  }
  atomicAdd(&sums[c], s1);        atomicAdd(&sums[OC + c], q1);
  atomicAdd(&sums[c + 256], s2);  atomicAdd(&sums[OC + c + 256], q2);
}

__global__ void k_bn_finalize(const float* __restrict__ sums,
                              const float* __restrict__ gamma,
                              const float* __restrict__ beta,
                              float* __restrict__ scale,
                              float* __restrict__ shift) {
  const int c = threadIdx.x;
  const float mean = sums[c] * (1.0f / NN);
  const float var  = sums[OC + c] * (1.0f / NN) - mean * mean;
  const float r    = rsqrtf(var + 1e-5f);
  const float sc   = r * gamma[c];
  scale[c] = sc;
  shift[c] = beta[c] - mean * sc;
}

__global__ void k_bn_apply(float* __restrict__ out,
                           const float* __restrict__ scale,
                           const float* __restrict__ shift) {
  const int i = blockIdx.x * blockDim.x + threadIdx.x;  // float4 index
  f32x4 v = *((const f32x4*)out + i);
  const int c = (i & 127) << 2;
  f32x4 r;
#pragma unroll
  for (int j = 0; j < 4; j++) r[j] = fmaxf(v[j] * scale[c + j] + shift[c + j], 0.0f);
  *((f32x4*)out + i) = r;
}

// ---------------------------------------------------------------------------
extern "C" void kernel_launch(void* const* d_in, const int* in_sizes, int n_in,
                              void* d_out, int out_size, void* d_ws, size_t ws_size,
                              hipStream_t stream) {
  const float* x     = (const float*)d_in[0];
  const int*   ei    = (const int*)d_in[1];   // [2][NE] int32 (harness-normalized)
  const float* ea    = (const float*)d_in[2];
  const float* W1    = (const float*)d_in[3];
  const float* b1    = (const float*)d_in[4];
  const float* W2    = (const float*)d_in[5];
  const float* b2    = (const float*)d_in[6];
  const float* gamma = (const float*)d_in[7];
  const float* beta  = (const float*)d_in[8];
  float* out = (float*)d_out;

  char* ws = (char*)d_ws;
  float*  agg    = (float*)(ws);                    // 20,480,000 B
  bf16_t* xb     = (bf16_t*)(ws + 20480000);        //  5,120,000 B
  bf16_t* w1t    = (bf16_t*)(ws + 25600000);        //    786,432 B
  bf16_t* w2t    = (bf16_t*)(ws + 26386432);        //    524,288 B
  int*    deg    = (int*)(ws + 26910720);           //     40,000 B
  int*    offs   = (int*)(ws + 26950720);           //     40,000 B
  int*    cursor = (int*)(ws + 26990720);           //     40,000 B
  float*  sums   = (float*)(ws + 27030720);         //      4,096 B
  float*  scale  = (float*)(ws + 27034816);         //      2,048 B
  float*  shift  = (float*)(ws + 27036864);         //      2,048 B
  int*    eperm  = (int*)(ws + 27038912);           //  1,280,000 B
  int*    sdst   = (int*)(ws + 28318912);           //  1,280,000 B
  int*    ssrc   = (int*)(ws + 29598912);           //  1,280,000 B

  const int* srcIdx = ei;        // edge_index[0]
  const int* dstIdx = ei + NE;   // edge_index[1]

  k_prep<<<4096, 256, 0, stream>>>(x, W1, W2, xb, w1t, w2t, agg, deg, cursor, sums);
  k_deg<<<(NE + 255) / 256, 256, 0, stream>>>(dstIdx, deg);
  k_scan<<<1, 256, 0, stream>>>(deg, offs);
  k_scatter<<<(NE + 255) / 256, 256, 0, stream>>>(srcIdx, dstIdx, offs, cursor,
                                                  eperm, sdst, ssrc);
  k_edge_gemm<<<(NE / 128) * 4, 256, 0, stream>>>(xb, ea, w1t, b1, eperm, sdst, ssrc, agg);
  k_node_gemm<<<((NN + 127) / 128) * 4, 256, 0, stream>>>(agg, w2t, b2, deg, out);
  k_bn_stats<<<256, 256, 0, stream>>>(out, sums);
  k_bn_finalize<<<1, 512, 0, stream>>>(sums, gamma, beta, scale, shift);
  k_bn_apply<<<(NN * OC / 4 + 255) / 256, 256, 0, stream>>>(out, scale, shift);
}

// Round 4
// 541.229 us; speedup vs baseline: 1.4041x; 1.1879x over previous
//
#include <hip/hip_runtime.h>
#include <hip/hip_bf16.h>
#include <cstdint>

// Problem constants (fixed by the reference)
#define NN 10000      // nodes
#define NE 320000     // edges
#define NC 256        // node channels
#define OC 512        // out channels
#define K1 256        // K for edge gemm (ea) and pq gemm (x)

typedef __bf16 bf16_t;
typedef bf16_t bf16x8 __attribute__((ext_vector_type(8)));
typedef float  f32x4  __attribute__((ext_vector_type(4)));

// async global->LDS, 16B per lane; LDS dest = wave-uniform base + lane*16
__device__ __forceinline__ void gload_lds16(const void* g, void* l) {
  __builtin_amdgcn_global_load_lds(
      (const __attribute__((address_space(1))) unsigned int*)g,
      (__attribute__((address_space(3))) unsigned int*)l, 16, 0, 0);
}

// ---------------------------------------------------------------------------
// Prep: zero agg/deg/cursor/sums, xb=bf16(x), build transposed bf16 weights:
//   w1abt[1024][256]: n<512 -> W1a' col n (W1a - W1b, folds x_j - x_i);
//                     n>=512 -> W1b col (n-512)
//   w1ct[512][256]:   W1c (ea part), w2t[512][512]: W2
// ---------------------------------------------------------------------------
__global__ void k_prep(const float* __restrict__ x,
                       const float* __restrict__ W1,
                       const float* __restrict__ W2,
                       bf16_t* __restrict__ xb,
                       bf16_t* __restrict__ w1abt,
                       bf16_t* __restrict__ w1ct,
                       bf16_t* __restrict__ w2t,
                       float* __restrict__ agg,
                       int* __restrict__ deg,
                       int* __restrict__ cursor,
                       float* __restrict__ sums) {
  const int stride = gridDim.x * blockDim.x;
  for (int i = blockIdx.x * blockDim.x + threadIdx.x; i < NN * OC; i += stride) {
    agg[i] = 0.0f;
    if (i < NN * NC) xb[i] = (bf16_t)x[i];
    if (i < 1024 * K1) {
      const int n = i >> 8, k = i & 255;
      float w;
      if (n < OC) w = W1[(size_t)k * OC + n] - W1[(size_t)(k + NC) * OC + n];
      else        w = W1[(size_t)(k + NC) * OC + (n - OC)];
      w1abt[i] = (bf16_t)w;
    }
    if (i < OC * K1) {
      const int n = i >> 8, k = i & 255;
      w1ct[i] = (bf16_t)W1[(size_t)(512 + k) * OC + n];
    }
    if (i < OC * OC) {
      const int n = i >> 9, k = i & 511;
      w2t[i] = (bf16_t)W2[(size_t)k * OC + n];
    }
    if (i < NN) { deg[i] = 0; cursor[i] = 0; }
    if (i < 1024) sums[i] = 0.0f;
  }
}

__global__ void k_deg(const int* __restrict__ dstIdx, int* __restrict__ deg) {
  const int i = blockIdx.x * blockDim.x + threadIdx.x;
  if (i < NE) atomicAdd(&deg[dstIdx[i]], 1);
}

// Single-block exclusive prefix sum over NN bins.
__global__ void k_scan(const int* __restrict__ deg, int* __restrict__ offs) {
  __shared__ int carry;
  __shared__ int wsum[4];
  if (threadIdx.x == 0) carry = 0;
  __syncthreads();
  const int lane = threadIdx.x & 63, w = threadIdx.x >> 6;
  for (int base = 0; base < NN; base += 256) {
    const int i = base + threadIdx.x;
    const int v = (i < NN) ? deg[i] : 0;
    int s = v;
#pragma unroll
    for (int d = 1; d < 64; d <<= 1) { int t = __shfl_up(s, d); if (lane >= d) s += t; }
    if (lane == 63) wsum[w] = s;
    __syncthreads();
    int woff = 0;
    for (int j = 0; j < w; j++) woff += wsum[j];
    const int incl = s + woff + carry;
    if (i < NN) offs[i] = incl - v;  // exclusive
    __syncthreads();
    if (threadIdx.x == 255) carry = incl;
    __syncthreads();
  }
}

// Counting-sort scatter: edges grouped by dst.
__global__ void k_scatter(const int* __restrict__ srcIdx, const int* __restrict__ dstIdx,
                          const int* __restrict__ offs, int* __restrict__ cursor,
                          int* __restrict__ eperm, int* __restrict__ sdst,
                          int* __restrict__ ssrc) {
  const int e = blockIdx.x * blockDim.x + threadIdx.x;
  if (e < NE) {
    const int d = dstIdx[e];
    const int pos = offs[d] + atomicAdd(&cursor[d], 1);
    eperm[pos] = e;
    sdst[pos] = d;
    ssrc[pos] = srcIdx[e];
  }
}

// ---------------------------------------------------------------------------
// Node-level PQ GEMM: [P | Q] = xb @ w1abt^T.  M=10000, K=256, N=1024.
// P (cols 0..511) stored fp32 with +b1 folded in; Q (cols 512..1023) bf16.
// 128x128 tile, 4 waves, global_load_lds + XOR slot swizzle on both tiles.
// ---------------------------------------------------------------------------
__global__ __launch_bounds__(256) void k_pq(
    const bf16_t* __restrict__ xb,     // [NN][256]
    const bf16_t* __restrict__ w1abt,  // [1024][256]
    const float*  __restrict__ b1,
    float*        __restrict__ P,      // [NN][512] fp32 (= x@W1a' + b1)
    bf16_t*       __restrict__ Qb) {   // [NN][512] bf16 (= x@W1b)
  __shared__ bf16_t sA[128 * 64];
  __shared__ bf16_t sB[128 * 64];

  const int tid = threadIdx.x;
  const int cb = blockIdx.x & 7, rblk = blockIdx.x >> 3;
  const int r0 = rblk * 128, n0 = cb * 128;
  const int lane = tid & 63, wid = tid >> 6;
  const int mbase = (wid >> 1) * 64, nbase = (wid & 1) * 64;
  const int lr = lane >> 3, ls = lane & 7, slog = ls ^ lr;
  const int g = lane >> 4;

  f32x4 acc[4][4];
#pragma unroll
  for (int mi = 0; mi < 4; mi++)
#pragma unroll
    for (int ni = 0; ni < 4; ni++) acc[mi][ni] = (f32x4){0.f, 0.f, 0.f, 0.f};

  for (int kb = 0; kb < K1; kb += 64) {
#pragma unroll
    for (int i = 0; i < 4; i++) {
      const int row = wid * 32 + i * 8;          // wave-uniform
      int grow = r0 + row + lr;                  // per-lane source row
      if (grow > NN - 1) grow = NN - 1;          // clamp (guarded on write)
      gload_lds16(xb + (size_t)grow * NC + kb + slog * 8, &sA[row * 64]);
      gload_lds16(w1abt + (size_t)(n0 + row + lr) * K1 + kb + slog * 8, &sB[row * 64]);
    }
    __syncthreads();
#pragma unroll
    for (int kk = 0; kk < 2; kk++) {
      const int sl = kk * 4 + g;
      bf16x8 av[4], bv[4];
#pragma unroll
      for (int mi = 0; mi < 4; mi++) {
        const int rA = mbase + mi * 16 + (lane & 15);
        av[mi] = *(const bf16x8*)&sA[rA * 64 + ((sl ^ (rA & 7)) * 8)];
      }
#pragma unroll
      for (int ni = 0; ni < 4; ni++) {
        const int rB = nbase + ni * 16 + (lane & 15);
        bv[ni] = *(const bf16x8*)&sB[rB * 64 + ((sl ^ (rB & 7)) * 8)];
      }
#pragma unroll
      for (int mi = 0; mi < 4; mi++)
#pragma unroll
        for (int ni = 0; ni < 4; ni++)
          acc[mi][ni] = __builtin_amdgcn_mfma_f32_16x16x32_bf16(av[mi], bv[ni], acc[mi][ni], 0, 0, 0);
    }
    __syncthreads();
  }

#pragma unroll
  for (int mi = 0; mi < 4; mi++) {
#pragma unroll
    for (int q = 0; q < 4; q++) {
      const int grow = r0 + mbase + mi * 16 + g * 4 + q;
      if (grow < NN) {
#pragma unroll
        for (int ni = 0; ni < 4; ni++) {
          const int ncol = n0 + nbase + ni * 16 + (lane & 15);
          const float v = acc[mi][ni][q];
          if (ncol < OC) P[(size_t)grow * OC + ncol] = v + b1[ncol];
          else           Qb[(size_t)grow * OC + (ncol - OC)] = (bf16_t)v;
        }
      }
    }
  }
}

// ---------------------------------------------------------------------------
// Edge GEMM v2: R = ea @ W1c only (K=256).  BM=128 edges, BN=256 cols,
// 8 waves.  Epilogue: relu(R + P[dst] + Q[src]) -> segmented reduce over
// sorted dst runs -> one atomicAdd per (run, col).
// W tile via global_load_lds (swizzled source); M tile fp32->bf16 VGPR
// staging with swizzled ds_write; all ds_read_b128 conflict-free.
// ---------------------------------------------------------------------------
__global__ __launch_bounds__(512) void k_edge_gemm(
    const float*  __restrict__ ea,     // [NE][256] f32
    const bf16_t* __restrict__ w1ct,   // [512][256] bf16
    const float*  __restrict__ P,      // [NN][512] f32 (b1 folded)
    const bf16_t* __restrict__ Qb,     // [NN][512] bf16
    const int*    __restrict__ eperm,
    const int*    __restrict__ sdst,
    const int*    __restrict__ ssrc,
    float*        __restrict__ agg) {  // [NN][512] f32
  __shared__ bf16_t sM[128 * 64];      // ea tile (16 KB)
  __shared__ bf16_t sW[256 * 64];      // W1c tile (32 KB)
  __shared__ int sDst[128];
  __shared__ int sSrc[128];
  __shared__ int sE[128];

  const int tid = threadIdx.x;
  const int cb = blockIdx.x & 1, eblk = blockIdx.x >> 1;
  const int e0 = eblk * 128, n0 = cb * 256;

  if (tid < 128) {
    sDst[tid] = sdst[e0 + tid];
    sSrc[tid] = ssrc[e0 + tid];
    sE[tid]   = eperm[e0 + tid];
  }
  __syncthreads();

  const int lane = tid & 63, wid = tid >> 6;
  const int mbase = (wid >> 2) * 64, nbase = (wid & 3) * 64;
  const int lr = lane >> 3, ls = lane & 7, slogW = ls ^ lr;
  const int g = lane >> 4;
  const int mrow = tid >> 2, qd = tid & 3;      // 4 threads/row, 16 elems each
  const int msw = mrow & 7;
  const float* eaRow = ea + (size_t)sE[mrow] * NC;

  f32x4 acc[4][4];
#pragma unroll
  for (int mi = 0; mi < 4; mi++)
#pragma unroll
    for (int ni = 0; ni < 4; ni++) acc[mi][ni] = (f32x4){0.f, 0.f, 0.f, 0.f};

  for (int kb = 0; kb < K1; kb += 64) {
    // ---- W tile: async global->LDS, source pre-swizzled ----
#pragma unroll
    for (int i = 0; i < 4; i++) {
      const int row = wid * 32 + i * 8;          // wave-uniform
      gload_lds16(w1ct + (size_t)(n0 + row + lr) * K1 + kb + slogW * 8, &sW[row * 64]);
    }
    // ---- M tile: fp32 ea -> bf16, swizzled ds_write ----
#pragma unroll
    for (int t = 0; t < 2; t++) {
      const int slog = qd * 2 + t;
      const float* pf = eaRow + kb + slog * 8;
      const f32x4 a = *(const f32x4*)pf, b = *(const f32x4*)(pf + 4);
      bf16x8 v;
#pragma unroll
      for (int j = 0; j < 4; j++) { v[j] = (bf16_t)a[j]; v[4 + j] = (bf16_t)b[j]; }
      *(bf16x8*)&sM[mrow * 64 + ((slog ^ msw) * 8)] = v;
    }
    __syncthreads();
    // ---- MFMA ----
#pragma unroll
    for (int kk = 0; kk < 2; kk++) {
      const int sl = kk * 4 + g;
      bf16x8 av[4], bv[4];
#pragma unroll
      for (int mi = 0; mi < 4; mi++) {
        const int rA = mbase + mi * 16 + (lane & 15);
        av[mi] = *(const bf16x8*)&sM[rA * 64 + ((sl ^ (rA & 7)) * 8)];
      }
#pragma unroll
      for (int ni = 0; ni < 4; ni++) {
        const int rB = nbase + ni * 16 + (lane & 15);
        bv[ni] = *(const bf16x8*)&sW[rB * 64 + ((sl ^ (rB & 7)) * 8)];
      }
#pragma unroll
      for (int mi = 0; mi < 4; mi++)
#pragma unroll
        for (int ni = 0; ni < 4; ni++)
          acc[mi][ni] = __builtin_amdgcn_mfma_f32_16x16x32_bf16(av[mi], bv[ni], acc[mi][ni], 0, 0, 0);
    }
    __syncthreads();
  }

  // ---- epilogue: relu(acc + P[dst] + Q[src]) -> segmented reduce ----
#pragma unroll
  for (int mi = 0; mi < 4; mi++) {
    const int rbase = mbase + mi * 16 + g * 4;   // first sorted row of my quad
    const int d0 = sDst[rbase],     d1 = sDst[rbase + 1];
    const int d2 = sDst[rbase + 2], d3 = sDst[rbase + 3];
    const int s0 = sSrc[rbase],     s1 = sSrc[rbase + 1];
    const int s2 = sSrc[rbase + 2], s3 = sSrc[rbase + 3];
    const int headId = d0, tailId = d3;
    const bool b1q = (d1 != d0), b2q = (d2 != d1), b3q = (d3 != d2);
    const bool seen = b1q | b2q | b3q;
    bool match[3];
#pragma unroll
    for (int j = 0; j < 3; j++) {
      const int tIdj = __shfl(tailId, (lane & 15) | (j << 4));
      match[j] = (j < g) && (tIdj == headId);
    }
    const int nextHead = __shfl(headId, (lane + 16) & 63);
    const bool endsHere = (g == 3) || (nextHead != tailId);

#pragma unroll
    for (int ni = 0; ni < 4; ni++) {
      const int col = n0 + nbase + ni * 16 + (lane & 15);
      const float* Pc = P + col;
      const bf16_t* Qc = Qb + col;
      const float v0 = fmaxf(acc[mi][ni][0] + Pc[(size_t)d0 * OC] + (float)Qc[(size_t)s0 * OC], 0.f);
      const float v1 = fmaxf(acc[mi][ni][1] + Pc[(size_t)d1 * OC] + (float)Qc[(size_t)s1 * OC], 0.f);
      const float v2 = fmaxf(acc[mi][ni][2] + Pc[(size_t)d2 * OC] + (float)Qc[(size_t)s2 * OC], 0.f);
      const float v3 = fmaxf(acc[mi][ni][3] + Pc[(size_t)d3 * OC] + (float)Qc[(size_t)s3 * OC], 0.f);
      // quad walk: head run, interior runs (flushed), tail run
      float head = 0.f, run = v0;
      bool first = true;
      if (b1q) { head = run; first = false; run = v1; } else run += v1;
      if (b2q) {
        if (first) { head = run; first = false; }
        else if (run != 0.f) atomicAdd(agg + (size_t)d1 * OC + col, run);
        run = v2;
      } else run += v2;
      if (b3q) {
        if (first) { head = run; first = false; }
        else if (run != 0.f) atomicAdd(agg + (size_t)d2 * OC + col, run);
        run = v3;
      } else run += v3;
      const float tailSum = run;
      float inc = 0.f;
#pragma unroll
      for (int j = 0; j < 3; j++) {
        const float ts = __shfl(tailSum, (lane & 15) | (j << 4));
        if (match[j]) inc += ts;
      }
      if (seen) {
        const float h = head + inc;
        if (h != 0.f) atomicAdd(agg + (size_t)headId * OC + col, h);
      }
      if (endsHere) {
        const float t = tailSum + (seen ? 0.f : inc);
        if (t != 0.f) atomicAdd(agg + (size_t)tailId * OC + col, t);
      }
    }
  }
}

// ---------------------------------------------------------------------------
// Node GEMM: out = agg @ W2 + deg * b2   (10000x512 @ 512x512)
// ---------------------------------------------------------------------------
__global__ __launch_bounds__(256) void k_node_gemm(
    const float*  __restrict__ agg,
    const bf16_t* __restrict__ w2t,    // [OC][OC] transposed
    const float*  __restrict__ b2,
    const int*    __restrict__ deg,
    float*        __restrict__ out) {
  __shared__ bf16_t sM[128 * 72];
  __shared__ bf16_t sW[128 * 72];

  const int tid  = threadIdx.x;
  const int bid  = blockIdx.x;
  const int cb   = bid & 3;
  const int rblk = bid >> 2;
  const int r0   = rblk * 128;
  const int n0   = cb * 128;

  const int lane  = tid & 63, wid = tid >> 6;
  const int mbase = (wid >> 1) * 64, nbase = (wid & 1) * 64;
  const int se = tid >> 1;
  const int sk = (tid & 1) * 32;
  const int arow  = r0 + se;
  const bool rowok = arow < NN;

  f32x4 acc[4][4];
#pragma unroll
  for (int mi = 0; mi < 4; mi++)
#pragma unroll
    for (int ni = 0; ni < 4; ni++) acc[mi][ni] = (f32x4){0.f, 0.f, 0.f, 0.f};

  for (int kb = 0; kb < OC; kb += 64) {
    {
      bf16x8* dst = (bf16x8*)&sM[se * 72 + sk];
      if (rowok) {
        const float* pf = agg + (size_t)arow * OC + kb + sk;
        f32x4 f[8];
#pragma unroll
        for (int i = 0; i < 8; i++) f[i] = *(const f32x4*)(pf + i * 4);
#pragma unroll
        for (int i = 0; i < 4; i++) {
          bf16x8 v;
#pragma unroll
          for (int j = 0; j < 4; j++) {
            v[j]     = (bf16_t)f[2 * i][j];
            v[4 + j] = (bf16_t)f[2 * i + 1][j];
          }
          dst[i] = v;
        }
      } else {
        bf16x8 z = {};
        dst[0] = z; dst[1] = z; dst[2] = z; dst[3] = z;
      }
    }
    {
      const bf16_t* pw = w2t + (size_t)(n0 + se) * OC + kb + sk;
      bf16x8* dst = (bf16x8*)&sW[se * 72 + sk];
      dst[0] = *(const bf16x8*)(pw);
      dst[1] = *(const bf16x8*)(pw + 8);
      dst[2] = *(const bf16x8*)(pw + 16);
      dst[3] = *(const bf16x8*)(pw + 24);
    }
    __syncthreads();
#pragma unroll
    for (int kk = 0; kk < 2; kk++) {
      const int krd = kk * 32 + (lane >> 4) * 8;
      bf16x8 av[4], bv[4];
#pragma unroll
      for (int mi = 0; mi < 4; mi++)
        av[mi] = *(const bf16x8*)&sM[(mbase + mi * 16 + (lane & 15)) * 72 + krd];
#pragma unroll
      for (int ni = 0; ni < 4; ni++)
        bv[ni] = *(const bf16x8*)&sW[(nbase + ni * 16 + (lane & 15)) * 72 + krd];
#pragma unroll
      for (int mi = 0; mi < 4; mi++)
#pragma unroll
        for (int ni = 0; ni < 4; ni++)
          acc[mi][ni] = __builtin_amdgcn_mfma_f32_16x16x32_bf16(av[mi], bv[ni], acc[mi][ni], 0, 0, 0);
    }
    __syncthreads();
  }

  float b2v[4];
#pragma unroll
  for (int ni = 0; ni < 4; ni++) b2v[ni] = b2[n0 + nbase + ni * 16 + (lane & 15)];
#pragma unroll
  for (int mi = 0; mi < 4; mi++) {
    const int rb = mbase + mi * 16 + (lane >> 4) * 4;
#pragma unroll
    for (int q = 0; q < 4; q++) {
      const int row = r0 + rb + q;
      if (row < NN) {
        const float dg = (float)deg[row];
        float* orow = out + (size_t)row * OC + n0 + nbase + (lane & 15);
#pragma unroll
        for (int ni = 0; ni < 4; ni++)
          orow[ni * 16] = acc[mi][ni][q] + b2v[ni] * dg;
      }
    }
  }
}

// ---------------------------------------------------------------------------
// BatchNorm: stats (sum, sumsq per channel), finalize, apply(+relu) in-place.
// ---------------------------------------------------------------------------
__global__ void k_bn_stats(const float* __restrict__ out, float* __restrict__ sums) {
  const int c = threadIdx.x;  // 256 threads -> channels c and c+256
  float s1 = 0.f, q1 = 0.f, s2 = 0.f, q2 = 0.f;
  for (int n = blockIdx.x; n < NN; n += gridDim.x) {
    const float* row = out + (size_t)n * OC;
    const float v1 = row[c], v2 = row[c + 256];
    s1 += v1; q1 += v1 * v1;
    s2 += v2; q2 += v2 * v2;
  }
  atomicAdd(&sums[c], s1);        atomicAdd(&sums[OC + c], q1);
  atomicAdd(&sums[c + 256], s2);  atomicAdd(&sums[OC + c + 256], q2);
}

__global__ void k_bn_finalize(const float* __restrict__ sums,
                              const float* __restrict__ gamma,
                              const float* __restrict__ beta,
                              float* __restrict__ scale,
                              float* __restrict__ shift) {
  const int c = threadIdx.x;
  const float mean = sums[c] * (1.0f / NN);
  const float var  = sums[OC + c] * (1.0f / NN) - mean * mean;
  const float r    = rsqrtf(var + 1e-5f);
  const float sc   = r * gamma[c];
  scale[c] = sc;
  shift[c] = beta[c] - mean * sc;
}

__global__ void k_bn_apply(float* __restrict__ out,
                           const float* __restrict__ scale,
                           const float* __restrict__ shift) {
  const int i = blockIdx.x * blockDim.x + threadIdx.x;  // float4 index
  f32x4 v = *((const f32x4*)out + i);
  const int c = (i & 127) << 2;
  f32x4 r;
#pragma unroll
  for (int j = 0; j < 4; j++) r[j] = fmaxf(v[j] * scale[c + j] + shift[c + j], 0.0f);
  *((f32x4*)out + i) = r;
}

// ---------------------------------------------------------------------------
extern "C" void kernel_launch(void* const* d_in, const int* in_sizes, int n_in,
                              void* d_out, int out_size, void* d_ws, size_t ws_size,
                              hipStream_t stream) {
  const float* x     = (const float*)d_in[0];
  const int*   ei    = (const int*)d_in[1];   // [2][NE] int32 (harness-normalized)
  const float* ea    = (const float*)d_in[2];
  const float* W1    = (const float*)d_in[3];
  const float* b1    = (const float*)d_in[4];
  const float* W2    = (const float*)d_in[5];
  const float* b2    = (const float*)d_in[6];
  const float* gamma = (const float*)d_in[7];
  const float* beta  = (const float*)d_in[8];
  float* out = (float*)d_out;

  char* ws = (char*)d_ws;
  float*  agg    = (float*)(ws);                    // 20,480,000 B
  float*  P      = (float*)(ws + 20480000);         // 20,480,000 B
  bf16_t* Qb     = (bf16_t*)(ws + 40960000);        // 10,240,000 B
  bf16_t* xb     = (bf16_t*)(ws + 51200000);        //  5,120,000 B
  bf16_t* w1abt  = (bf16_t*)(ws + 56320000);        //    524,288 B
  bf16_t* w1ct   = (bf16_t*)(ws + 56844288);        //    262,144 B
  bf16_t* w2t    = (bf16_t*)(ws + 57106432);        //    524,288 B
  int*    deg    = (int*)(ws + 57630720);           //     40,000 B
  int*    offs   = (int*)(ws + 57670720);           //     40,000 B
  int*    cursor = (int*)(ws + 57710720);           //     40,000 B
  float*  sums   = (float*)(ws + 57750720);         //      4,096 B
  float*  scale  = (float*)(ws + 57754816);         //      2,048 B
  float*  shift  = (float*)(ws + 57756864);         //      2,048 B
  int*    eperm  = (int*)(ws + 57758912);           //  1,280,000 B
  int*    sdst   = (int*)(ws + 59038912);           //  1,280,000 B
  int*    ssrc   = (int*)(ws + 60318912);           //  1,280,000 B

  const int* srcIdx = ei;        // edge_index[0]
  const int* dstIdx = ei + NE;   // edge_index[1]

  k_prep<<<4096, 256, 0, stream>>>(x, W1, W2, xb, w1abt, w1ct, w2t, agg, deg, cursor, sums);
  k_deg<<<(NE + 255) / 256, 256, 0, stream>>>(dstIdx, deg);
  k_scan<<<1, 256, 0, stream>>>(deg, offs);
  k_scatter<<<(NE + 255) / 256, 256, 0, stream>>>(srcIdx, dstIdx, offs, cursor,
                                                  eperm, sdst, ssrc);
  k_pq<<<((NN + 127) / 128) * 8, 256, 0, stream>>>(xb, w1abt, b1, P, Qb);
  k_edge_gemm<<<(NE / 128) * 2, 512, 0, stream>>>(ea, w1ct, P, Qb, eperm, sdst, ssrc, agg);
  k_node_gemm<<<((NN + 127) / 128) * 4, 256, 0, stream>>>(agg, w2t, b2, deg, out);
  k_bn_stats<<<256, 256, 0, stream>>>(out, sums);
  k_bn_finalize<<<1, 512, 0, stream>>>(sums, gamma, beta, scale, shift);
  k_bn_apply<<<(NN * OC / 4 + 255) / 256, 256, 0, stream>>>(out, scale, shift);
}

// Round 5
// 534.868 us; speedup vs baseline: 1.4208x; 1.0119x over previous
//
#include <hip/hip_runtime.h>
#include <hip/hip_bf16.h>
#include <cstdint>

// Problem constants (fixed by the reference)
#define NN 10000      // nodes
#define NE 320000     // edges
#define NC 256        // node channels
#define OC 512        // out channels
#define K1 256        // K for edge gemm (ea) and pq gemm (x)

typedef __bf16 bf16_t;
typedef bf16_t bf16x8 __attribute__((ext_vector_type(8)));
typedef bf16_t bf16x4 __attribute__((ext_vector_type(4)));
typedef float  f32x4  __attribute__((ext_vector_type(4)));

// async global->LDS, 16B per lane; LDS dest = wave-uniform base + lane*16
__device__ __forceinline__ void gload_lds16(const void* g, void* l) {
  __builtin_amdgcn_global_load_lds(
      (const __attribute__((address_space(1))) unsigned int*)g,
      (__attribute__((address_space(3))) unsigned int*)l, 16, 0, 0);
}

// B-side column interleave: LDS tile row R holds the weight row for logical
// column (R&~63) + (R&15)*4 + ((R>>4)&3).  This makes each lane's 4 MFMA
// fragments cover 4 CONSECUTIVE output columns -> vector epilogue.
__device__ __forceinline__ int permB(int R) {
  return (R & ~63) + ((R & 15) << 2) + ((R >> 4) & 3);
}

// ---------------------------------------------------------------------------
// Prep: zero agg/deg/cursor/sums, xb=bf16(x), build transposed bf16 weights:
//   w1abt[1024][256]: n<512 -> W1a' col n (W1a - W1b, folds x_j - x_i);
//                     n>=512 -> W1b col (n-512)
//   w1ct[512][256]:   W1c (ea part), w2t[512][512]: W2
// ---------------------------------------------------------------------------
__global__ void k_prep(const float* __restrict__ x,
                       const float* __restrict__ W1,
                       const float* __restrict__ W2,
                       bf16_t* __restrict__ xb,
                       bf16_t* __restrict__ w1abt,
                       bf16_t* __restrict__ w1ct,
                       bf16_t* __restrict__ w2t,
                       float* __restrict__ agg,
                       int* __restrict__ deg,
                       int* __restrict__ cursor,
                       float* __restrict__ sums) {
  const int stride = gridDim.x * blockDim.x;
  for (int i = blockIdx.x * blockDim.x + threadIdx.x; i < NN * OC; i += stride) {
    agg[i] = 0.0f;
    if (i < NN * NC) xb[i] = (bf16_t)x[i];
    if (i < 1024 * K1) {
      const int n = i >> 8, k = i & 255;
      float w;
      if (n < OC) w = W1[(size_t)k * OC + n] - W1[(size_t)(k + NC) * OC + n];
      else        w = W1[(size_t)(k + NC) * OC + (n - OC)];
      w1abt[i] = (bf16_t)w;
    }
    if (i < OC * K1) {
      const int n = i >> 8, k = i & 255;
      w1ct[i] = (bf16_t)W1[(size_t)(512 + k) * OC + n];
    }
    if (i < OC * OC) {
      const int n = i >> 9, k = i & 511;
      w2t[i] = (bf16_t)W2[(size_t)k * OC + n];
    }
    if (i < NN) { deg[i] = 0; cursor[i] = 0; }
    if (i < 1024) sums[i] = 0.0f;
  }
}

__global__ void k_deg(const int* __restrict__ dstIdx, int* __restrict__ deg) {
  const int i = blockIdx.x * blockDim.x + threadIdx.x;
  if (i < NE) atomicAdd(&deg[dstIdx[i]], 1);
}

// Single-block exclusive prefix sum over NN bins.
__global__ void k_scan(const int* __restrict__ deg, int* __restrict__ offs) {
  __shared__ int carry;
  __shared__ int wsum[4];
  if (threadIdx.x == 0) carry = 0;
  __syncthreads();
  const int lane = threadIdx.x & 63, w = threadIdx.x >> 6;
  for (int base = 0; base < NN; base += 256) {
    const int i = base + threadIdx.x;
    const int v = (i < NN) ? deg[i] : 0;
    int s = v;
#pragma unroll
    for (int d = 1; d < 64; d <<= 1) { int t = __shfl_up(s, d); if (lane >= d) s += t; }
    if (lane == 63) wsum[w] = s;
    __syncthreads();
    int woff = 0;
    for (int j = 0; j < w; j++) woff += wsum[j];
    const int incl = s + woff + carry;
    if (i < NN) offs[i] = incl - v;  // exclusive
    __syncthreads();
    if (threadIdx.x == 255) carry = incl;
    __syncthreads();
  }
}

// Counting-sort scatter: edges grouped by dst.
__global__ void k_scatter(const int* __restrict__ srcIdx, const int* __restrict__ dstIdx,
                          const int* __restrict__ offs, int* __restrict__ cursor,
                          int* __restrict__ eperm, int* __restrict__ sdst,
                          int* __restrict__ ssrc) {
  const int e = blockIdx.x * blockDim.x + threadIdx.x;
  if (e < NE) {
    const int d = dstIdx[e];
    const int pos = offs[d] + atomicAdd(&cursor[d], 1);
    eperm[pos] = e;
    sdst[pos] = d;
    ssrc[pos] = srcIdx[e];
  }
}

// ---------------------------------------------------------------------------
// Node-level PQ GEMM: [P | Q] = xb @ w1abt^T.  M=10000, K=256, N=1024.
// P (cols 0..511) fp32 with +b1 folded; Q (cols 512..1023) bf16.
// 128x128 tile, 4 waves, global_load_lds + XOR swizzle + col-interleave.
// ---------------------------------------------------------------------------
__global__ __launch_bounds__(256) void k_pq(
    const bf16_t* __restrict__ xb,     // [NN][256]
    const bf16_t* __restrict__ w1abt,  // [1024][256]
    const float*  __restrict__ b1,
    float*        __restrict__ P,      // [NN][512] fp32 (= x@W1a' + b1)
    bf16_t*       __restrict__ Qb) {   // [NN][512] bf16 (= x@W1b)
  __shared__ bf16_t sA[128 * 64];
  __shared__ bf16_t sB[128 * 64];

  const int tid = threadIdx.x;
  const int cb = blockIdx.x & 7, rblk = blockIdx.x >> 3;
  const int r0 = rblk * 128, n0 = cb * 128;
  const int lane = tid & 63, wid = tid >> 6;
  const int mbase = (wid >> 1) * 64, nbase = (wid & 1) * 64;
  const int lr = lane >> 3, ls = lane & 7, slog = ls ^ lr;
  const int g = lane >> 4;

  f32x4 acc[4][4];
#pragma unroll
  for (int mi = 0; mi < 4; mi++)
#pragma unroll
    for (int ni = 0; ni < 4; ni++) acc[mi][ni] = (f32x4){0.f, 0.f, 0.f, 0.f};

  for (int kb = 0; kb < K1; kb += 64) {
#pragma unroll
    for (int i = 0; i < 4; i++) {
      const int row = wid * 32 + i * 8;          // wave-uniform
      int grow = r0 + row + lr;                  // per-lane source row
      if (grow > NN - 1) grow = NN - 1;          // clamp (guarded on write)
      gload_lds16(xb + (size_t)grow * NC + kb + slog * 8, &sA[row * 64]);
      gload_lds16(w1abt + (size_t)(n0 + permB(row + lr)) * K1 + kb + slog * 8,
                  &sB[row * 64]);
    }
    __syncthreads();
#pragma unroll
    for (int kk = 0; kk < 2; kk++) {
      const int sl = kk * 4 + g;
      bf16x8 av[4], bv[4];
#pragma unroll
      for (int mi = 0; mi < 4; mi++) {
        const int rA = mbase + mi * 16 + (lane & 15);
        av[mi] = *(const bf16x8*)&sA[rA * 64 + ((sl ^ (rA & 7)) * 8)];
      }
#pragma unroll
      for (int ni = 0; ni < 4; ni++) {
        const int rB = nbase + ni * 16 + (lane & 15);
        bv[ni] = *(const bf16x8*)&sB[rB * 64 + ((sl ^ (rB & 7)) * 8)];
      }
#pragma unroll
      for (int mi = 0; mi < 4; mi++)
#pragma unroll
        for (int ni = 0; ni < 4; ni++)
          acc[mi][ni] = __builtin_amdgcn_mfma_f32_16x16x32_bf16(av[mi], bv[ni], acc[mi][ni], 0, 0, 0);
    }
    __syncthreads();
  }

  // epilogue: lane's 4 fragments = consecutive logical cols col0..col0+3
  const int col0 = n0 + nbase + (lane & 15) * 4;
  f32x4 b1v = {0.f, 0.f, 0.f, 0.f};
  if (col0 < OC) b1v = *(const f32x4*)&b1[col0];
#pragma unroll
  for (int mi = 0; mi < 4; mi++) {
#pragma unroll
    for (int q = 0; q < 4; q++) {
      const int grow = r0 + mbase + mi * 16 + g * 4 + q;
      if (grow < NN) {
        if (col0 < OC) {
          f32x4 v;
#pragma unroll
          for (int j = 0; j < 4; j++) v[j] = acc[mi][j][q] + b1v[j];
          *(f32x4*)&P[(size_t)grow * OC + col0] = v;
        } else {
          bf16x4 v;
#pragma unroll
          for (int j = 0; j < 4; j++) v[j] = (bf16_t)acc[mi][j][q];
          *(bf16x4*)&Qb[(size_t)grow * OC + (col0 - OC)] = v;
        }
      }
    }
  }
}

// ---------------------------------------------------------------------------
// Edge GEMM: R = ea @ W1c (K=256).  BM=128 edges, BN=256 cols, 8 waves.
// Col-interleaved B -> vector epilogue: relu(R + P[dst] + Q[src]) with
// f32x4/bf16x4 gathers, segmented reduce over sorted dst, atomics per run.
// ---------------------------------------------------------------------------
__global__ __launch_bounds__(512) void k_edge_gemm(
    const float*  __restrict__ ea,     // [NE][256] f32
    const bf16_t* __restrict__ w1ct,   // [512][256] bf16
    const float*  __restrict__ P,      // [NN][512] f32 (b1 folded)
    const bf16_t* __restrict__ Qb,     // [NN][512] bf16
    const int*    __restrict__ eperm,
    const int*    __restrict__ sdst,
    const int*    __restrict__ ssrc,
    float*        __restrict__ agg) {  // [NN][512] f32
  __shared__ bf16_t sM[128 * 64];      // ea tile (16 KB)
  __shared__ bf16_t sW[256 * 64];      // W1c tile (32 KB)
  __shared__ int sDst[128];
  __shared__ int sSrc[128];
  __shared__ int sE[128];

  const int tid = threadIdx.x;
  const int cb = blockIdx.x & 1, eblk = blockIdx.x >> 1;
  const int e0 = eblk * 128, n0 = cb * 256;

  if (tid < 128) {
    sDst[tid] = sdst[e0 + tid];
    sSrc[tid] = ssrc[e0 + tid];
    sE[tid]   = eperm[e0 + tid];
  }
  __syncthreads();

  const int lane = tid & 63, wid = tid >> 6;
  const int mbase = (wid >> 2) * 64, nbase = (wid & 3) * 64;
  const int lr = lane >> 3, ls = lane & 7, slogW = ls ^ lr;
  const int g = lane >> 4;
  const int mrow = tid >> 2, qd = tid & 3;      // 4 threads/row, 16 elems each
  const int msw = mrow & 7;
  const float* eaRow = ea + (size_t)sE[mrow] * NC;

  f32x4 acc[4][4];
#pragma unroll
  for (int mi = 0; mi < 4; mi++)
#pragma unroll
    for (int ni = 0; ni < 4; ni++) acc[mi][ni] = (f32x4){0.f, 0.f, 0.f, 0.f};

  for (int kb = 0; kb < K1; kb += 64) {
    // ---- W tile: async global->LDS, col-interleaved + swizzled source ----
#pragma unroll
    for (int i = 0; i < 4; i++) {
      const int row = wid * 32 + i * 8;          // wave-uniform
      gload_lds16(w1ct + (size_t)(n0 + permB(row + lr)) * K1 + kb + slogW * 8,
                  &sW[row * 64]);
    }
    // ---- M tile: fp32 ea -> bf16, swizzled ds_write ----
#pragma unroll
    for (int t = 0; t < 2; t++) {
      const int slog = qd * 2 + t;
      const float* pf = eaRow + kb + slog * 8;
      const f32x4 a = *(const f32x4*)pf, b = *(const f32x4*)(pf + 4);
      bf16x8 v;
#pragma unroll
      for (int j = 0; j < 4; j++) { v[j] = (bf16_t)a[j]; v[4 + j] = (bf16_t)b[j]; }
      *(bf16x8*)&sM[mrow * 64 + ((slog ^ msw) * 8)] = v;
    }
    __syncthreads();
    // ---- MFMA ----
#pragma unroll
    for (int kk = 0; kk < 2; kk++) {
      const int sl = kk * 4 + g;
      bf16x8 av[4], bv[4];
#pragma unroll
      for (int mi = 0; mi < 4; mi++) {
        const int rA = mbase + mi * 16 + (lane & 15);
        av[mi] = *(const bf16x8*)&sM[rA * 64 + ((sl ^ (rA & 7)) * 8)];
      }
#pragma unroll
      for (int ni = 0; ni < 4; ni++) {
        const int rB = nbase + ni * 16 + (lane & 15);
        bv[ni] = *(const bf16x8*)&sW[rB * 64 + ((sl ^ (rB & 7)) * 8)];
      }
#pragma unroll
      for (int mi = 0; mi < 4; mi++)
#pragma unroll
        for (int ni = 0; ni < 4; ni++)
          acc[mi][ni] = __builtin_amdgcn_mfma_f32_16x16x32_bf16(av[mi], bv[ni], acc[mi][ni], 0, 0, 0);
    }
    __syncthreads();
  }

  // ---- epilogue: relu(acc + P[dst] + Q[src]) -> segmented reduce ----
  const int col0 = n0 + nbase + (lane & 15) * 4;  // 4 consecutive cols/lane
#pragma unroll
  for (int mi = 0; mi < 4; mi++) {
    const int rbase = mbase + mi * 16 + g * 4;   // first sorted row of my quad
    const int d0 = sDst[rbase],     d1 = sDst[rbase + 1];
    const int d2 = sDst[rbase + 2], d3 = sDst[rbase + 3];
    const int s0 = sSrc[rbase],     s1 = sSrc[rbase + 1];
    const int s2 = sSrc[rbase + 2], s3 = sSrc[rbase + 3];
    const int headId = d0, tailId = d3;
    const bool b1q = (d1 != d0), b2q = (d2 != d1), b3q = (d3 != d2);
    const bool seen = b1q | b2q | b3q;
    bool match[3];
#pragma unroll
    for (int j = 0; j < 3; j++) {
      const int tIdj = __shfl(tailId, (lane & 15) | (j << 4));
      match[j] = (j < g) && (tIdj == headId);
    }
    const int nextHead = __shfl(headId, (lane + 16) & 63);
    const bool endsHere = (g == 3) || (nextHead != tailId);

    // vector gathers: P f32x4, Q bf16x4 per quad row
    const f32x4 P0 = *(const f32x4*)&P[(size_t)d0 * OC + col0];
    const f32x4 P1 = *(const f32x4*)&P[(size_t)d1 * OC + col0];
    const f32x4 P2 = *(const f32x4*)&P[(size_t)d2 * OC + col0];
    const f32x4 P3 = *(const f32x4*)&P[(size_t)d3 * OC + col0];
    const bf16x4 Q0 = *(const bf16x4*)&Qb[(size_t)s0 * OC + col0];
    const bf16x4 Q1 = *(const bf16x4*)&Qb[(size_t)s1 * OC + col0];
    const bf16x4 Q2 = *(const bf16x4*)&Qb[(size_t)s2 * OC + col0];
    const bf16x4 Q3 = *(const bf16x4*)&Qb[(size_t)s3 * OC + col0];

    f32x4 v0, v1, v2, v3;
#pragma unroll
    for (int j = 0; j < 4; j++) {
      v0[j] = fmaxf(acc[mi][j][0] + P0[j] + (float)Q0[j], 0.f);
      v1[j] = fmaxf(acc[mi][j][1] + P1[j] + (float)Q1[j], 0.f);
      v2[j] = fmaxf(acc[mi][j][2] + P2[j] + (float)Q2[j], 0.f);
      v3[j] = fmaxf(acc[mi][j][3] + P3[j] + (float)Q3[j], 0.f);
    }

    // quad walk (element-wise on f32x4): head run, interior flushes, tail run
    f32x4 head = {0.f, 0.f, 0.f, 0.f}, run = v0;
    bool first = true;
    if (b1q) { head = run; first = false; run = v1; } else run += v1;
    if (b2q) {
      if (first) { head = run; first = false; }
      else {
        float* base = agg + (size_t)d1 * OC + col0;
#pragma unroll
        for (int j = 0; j < 4; j++) if (run[j] != 0.f) atomicAdd(base + j, run[j]);
      }
      run = v2;
    } else run += v2;
    if (b3q) {
      if (first) { head = run; first = false; }
      else {
        float* base = agg + (size_t)d2 * OC + col0;
#pragma unroll
        for (int j = 0; j < 4; j++) if (run[j] != 0.f) atomicAdd(base + j, run[j]);
      }
      run = v3;
    } else run += v3;
    const f32x4 tailSum = run;

    f32x4 inc = {0.f, 0.f, 0.f, 0.f};
#pragma unroll
    for (int jg = 0; jg < 3; jg++) {
      f32x4 ts;
#pragma unroll
      for (int c = 0; c < 4; c++) ts[c] = __shfl(tailSum[c], (lane & 15) | (jg << 4));
      if (match[jg]) inc += ts;
    }
    if (seen) {
      float* base = agg + (size_t)headId * OC + col0;
#pragma unroll
      for (int j = 0; j < 4; j++) {
        const float h = head[j] + inc[j];
        if (h != 0.f) atomicAdd(base + j, h);
      }
    }
    if (endsHere) {
      float* base = agg + (size_t)tailId * OC + col0;
#pragma unroll
      for (int j = 0; j < 4; j++) {
        const float t = tailSum[j] + (seen ? 0.f : inc[j]);
        if (t != 0.f) atomicAdd(base + j, t);
      }
    }
  }
}

// ---------------------------------------------------------------------------
// Node GEMM: out = agg @ W2 + deg * b2   (10000x512 @ 512x512)
// Col-interleaved B -> vector f32x4 epilogue stores.
// ---------------------------------------------------------------------------
__global__ __launch_bounds__(256) void k_node_gemm(
    const float*  __restrict__ agg,
    const bf16_t* __restrict__ w2t,    // [OC][OC] transposed
    const float*  __restrict__ b2,
    const int*    __restrict__ deg,
    float*        __restrict__ out) {
  __shared__ bf16_t sM[128 * 72];
  __shared__ bf16_t sW[128 * 72];

  const int tid  = threadIdx.x;
  const int bid  = blockIdx.x;
  const int cb   = bid & 3;
  const int rblk = bid >> 2;
  const int r0   = rblk * 128;
  const int n0   = cb * 128;

  const int lane  = tid & 63, wid = tid >> 6;
  const int mbase = (wid >> 1) * 64, nbase = (wid & 1) * 64;
  const int se = tid >> 1;
  const int sk = (tid & 1) * 32;
  const int arow  = r0 + se;
  const bool rowok = arow < NN;

  f32x4 acc[4][4];
#pragma unroll
  for (int mi = 0; mi < 4; mi++)
#pragma unroll
    for (int ni = 0; ni < 4; ni++) acc[mi][ni] = (f32x4){0.f, 0.f, 0.f, 0.f};

  for (int kb = 0; kb < OC; kb += 64) {
    {
      bf16x8* dst = (bf16x8*)&sM[se * 72 + sk];
      if (rowok) {
        const float* pf = agg + (size_t)arow * OC + kb + sk;
        f32x4 f[8];
#pragma unroll
        for (int i = 0; i < 8; i++) f[i] = *(const f32x4*)(pf + i * 4);
#pragma unroll
        for (int i = 0; i < 4; i++) {
          bf16x8 v;
#pragma unroll
          for (int j = 0; j < 4; j++) {
            v[j]     = (bf16_t)f[2 * i][j];
            v[4 + j] = (bf16_t)f[2 * i + 1][j];
          }
          dst[i] = v;
        }
      } else {
        bf16x8 z = {};
        dst[0] = z; dst[1] = z; dst[2] = z; dst[3] = z;
      }
    }
    {
      const bf16_t* pw = w2t + (size_t)(n0 + permB(se)) * OC + kb + sk;
      bf16x8* dst = (bf16x8*)&sW[se * 72 + sk];
      dst[0] = *(const bf16x8*)(pw);
      dst[1] = *(const bf16x8*)(pw + 8);
      dst[2] = *(const bf16x8*)(pw + 16);
      dst[3] = *(const bf16x8*)(pw + 24);
    }
    __syncthreads();
#pragma unroll
    for (int kk = 0; kk < 2; kk++) {
      const int krd = kk * 32 + (lane >> 4) * 8;
      bf16x8 av[4], bv[4];
#pragma unroll
      for (int mi = 0; mi < 4; mi++)
        av[mi] = *(const bf16x8*)&sM[(mbase + mi * 16 + (lane & 15)) * 72 + krd];
#pragma unroll
      for (int ni = 0; ni < 4; ni++)
        bv[ni] = *(const bf16x8*)&sW[(nbase + ni * 16 + (lane & 15)) * 72 + krd];
#pragma unroll
      for (int mi = 0; mi < 4; mi++)
#pragma unroll
        for (int ni = 0; ni < 4; ni++)
          acc[mi][ni] = __builtin_amdgcn_mfma_f32_16x16x32_bf16(av[mi], bv[ni], acc[mi][ni], 0, 0, 0);
    }
    __syncthreads();
  }

  const int col0 = n0 + nbase + (lane & 15) * 4;
  const f32x4 b2v = *(const f32x4*)&b2[col0];
  const int g = lane >> 4;
#pragma unroll
  for (int mi = 0; mi < 4; mi++) {
#pragma unroll
    for (int q = 0; q < 4; q++) {
      const int row = r0 + mbase + mi * 16 + g * 4 + q;
      if (row < NN) {
        const float dg = (float)deg[row];
        f32x4 v;
#pragma unroll
        for (int j = 0; j < 4; j++) v[j] = acc[mi][j][q] + b2v[j] * dg;
        *(f32x4*)&out[(size_t)row * OC + col0] = v;
      }
    }
  }
}

// ---------------------------------------------------------------------------
// BatchNorm: stats (sum, sumsq per channel), finalize, apply(+relu) in-place.
// ---------------------------------------------------------------------------
__global__ void k_bn_stats(const float* __restrict__ out, float* __restrict__ sums) {
  const int c = threadIdx.x;  // 256 threads -> channels c and c+256
  float s1 = 0.f, q1 = 0.f, s2 = 0.f, q2 = 0.f;
  for (int n = blockIdx.x; n < NN; n += gridDim.x) {
    const float* row = out + (size_t)n * OC;
    const float v1 = row[c], v2 = row[c + 256];
    s1 += v1; q1 += v1 * v1;
    s2 += v2; q2 += v2 * v2;
  }
  atomicAdd(&sums[c], s1);        atomicAdd(&sums[OC + c], q1);
  atomicAdd(&sums[c + 256], s2);  atomicAdd(&sums[OC + c + 256], q2);
}

__global__ void k_bn_finalize(const float* __restrict__ sums,
                              const float* __restrict__ gamma,
                              const float* __restrict__ beta,
                              float* __restrict__ scale,
                              float* __restrict__ shift) {
  const int c = threadIdx.x;
  const float mean = sums[c] * (1.0f / NN);
  const float var  = sums[OC + c] * (1.0f / NN) - mean * mean;
  const float r    = rsqrtf(var + 1e-5f);
  const float sc   = r * gamma[c];
  scale[c] = sc;
  shift[c] = beta[c] - mean * sc;
}

__global__ void k_bn_apply(float* __restrict__ out,
                           const float* __restrict__ scale,
                           const float* __restrict__ shift) {
  const int i = blockIdx.x * blockDim.x + threadIdx.x;  // float4 index
  f32x4 v = *((const f32x4*)out + i);
  const int c = (i & 127) << 2;
  f32x4 r;
#pragma unroll
  for (int j = 0; j < 4; j++) r[j] = fmaxf(v[j] * scale[c + j] + shift[c + j], 0.0f);
  *((f32x4*)out + i) = r;
}

// ---------------------------------------------------------------------------
extern "C" void kernel_launch(void* const* d_in, const int* in_sizes, int n_in,
                              void* d_out, int out_size, void* d_ws, size_t ws_size,
                              hipStream_t stream) {
  const float* x     = (const float*)d_in[0];
  const int*   ei    = (const int*)d_in[1];   // [2][NE] int32 (harness-normalized)
  const float* ea    = (const float*)d_in[2];
  const float* W1    = (const float*)d_in[3];
  const float* b1    = (const float*)d_in[4];
  const float* W2    = (const float*)d_in[5];
  const float* b2    = (const float*)d_in[6];
  const float* gamma = (const float*)d_in[7];
  const float* beta  = (const float*)d_in[8];
  float* out = (float*)d_out;

  char* ws = (char*)d_ws;
  float*  agg    = (float*)(ws);                    // 20,480,000 B
  float*  P      = (float*)(ws + 20480000);         // 20,480,000 B
  bf16_t* Qb     = (bf16_t*)(ws + 40960000);        // 10,240,000 B
  bf16_t* xb     = (bf16_t*)(ws + 51200000);        //  5,120,000 B
  bf16_t* w1abt  = (bf16_t*)(ws + 56320000);        //    524,288 B
  bf16_t* w1ct   = (bf16_t*)(ws + 56844288);        //    262,144 B
  bf16_t* w2t    = (bf16_t*)(ws + 57106432);        //    524,288 B
  int*    deg    = (int*)(ws + 57630720);           //     40,000 B
  int*    offs   = (int*)(ws + 57670720);           //     40,000 B
  int*    cursor = (int*)(ws + 57710720);           //     40,000 B
  float*  sums   = (float*)(ws + 57750720);         //      4,096 B
  float*  scale  = (float*)(ws + 57754816);         //      2,048 B
  float*  shift  = (float*)(ws + 57756864);         //      2,048 B
  int*    eperm  = (int*)(ws + 57758912);           //  1,280,000 B
  int*    sdst   = (int*)(ws + 59038912);           //  1,280,000 B
  int*    ssrc   = (int*)(ws + 60318912);           //  1,280,000 B

  const int* srcIdx = ei;        // edge_index[0]
  const int* dstIdx = ei + NE;   // edge_index[1]

  k_prep<<<4096, 256, 0, stream>>>(x, W1, W2, xb, w1abt, w1ct, w2t, agg, deg, cursor, sums);
  k_deg<<<(NE + 255) / 256, 256, 0, stream>>>(dstIdx, deg);
  k_scan<<<1, 256, 0, stream>>>(deg, offs);
  k_scatter<<<(NE + 255) / 256, 256, 0, stream>>>(srcIdx, dstIdx, offs, cursor,
                                                  eperm, sdst, ssrc);
  k_pq<<<((NN + 127) / 128) * 8, 256, 0, stream>>>(xb, w1abt, b1, P, Qb);
  k_edge_gemm<<<(NE / 128) * 2, 512, 0, stream>>>(ea, w1ct, P, Qb, eperm, sdst, ssrc, agg);
  k_node_gemm<<<((NN + 127) / 128) * 4, 256, 0, stream>>>(agg, w2t, b2, deg, out);
  k_bn_stats<<<256, 256, 0, stream>>>(out, sums);
  k_bn_finalize<<<1, 512, 0, stream>>>(sums, gamma, beta, scale, shift);
  k_bn_apply<<<(NN * OC / 4 + 255) / 256, 256, 0, stream>>>(out, scale, shift);
}